// Round 10
// baseline (5168.462 us; speedup 1.0000x reference)
//
#include <hip/hip_runtime.h>
#include <cstdint>

typedef float f32x4 __attribute__((ext_vector_type(4)));
typedef __bf16 bf16x8 __attribute__((ext_vector_type(8)));
typedef __bf16 bf16x4 __attribute__((ext_vector_type(4)));

#define NB 512
#define GRP 32
#define NGRP (NB / GRP)

// bar layout (uints): [0 .. NGRP*32)  group counters (128B apart)
//                     [NGRP*32]      root counter
//                     [1024 .. 1024 + NB*32) per-block flags (128B apart)
#define BAR_UINTS (1024 + NB * 32)

struct LayerP {
    const float* src; const __bf16* w_in;
    const float* convw; const float* convb;
    const __bf16* w_xp; const float* dtw; const float* dtb;
    const float* Alog; const float* Dp; const __bf16* w_out;
    float* dst; const float* resid;
    int M, DM, DI, R, P, KS, Lb, tr;
};

struct MegaP {
    unsigned* bar;
    float *xz, *xi, *xdbl, *dtbuf, *y, *pk, *wsA, *wsB;
    const float* cs[5]; __bf16* cd[5]; int cn[5];
    const float* xpb; __bf16* xpb_d;
    LayerP L[4];
};

__device__ __forceinline__ void gbar(unsigned* bar, unsigned gen)
{
    __shared__ unsigned s_role;
    const int bid = blockIdx.x;
    __syncthreads();
    if (threadIdx.x == 0) {
        __threadfence();
        unsigned role = 0;
        unsigned* gcnt = bar + (bid / GRP) * 32;
        unsigned old = __hip_atomic_fetch_add(gcnt, 1u, __ATOMIC_ACQ_REL, __HIP_MEMORY_SCOPE_AGENT);
        if (old == GRP - 1) {
            __hip_atomic_store(gcnt, 0u, __ATOMIC_RELAXED, __HIP_MEMORY_SCOPE_AGENT);
            unsigned r = __hip_atomic_fetch_add(bar + NGRP * 32, 1u, __ATOMIC_ACQ_REL, __HIP_MEMORY_SCOPE_AGENT);
            if (r == NGRP - 1) {
                __hip_atomic_store(bar + NGRP * 32, 0u, __ATOMIC_RELAXED, __HIP_MEMORY_SCOPE_AGENT);
                role = 1;
            }
        }
        s_role = role;
    }
    __syncthreads();
    unsigned* flags = bar + 1024;
    if (s_role) {
        for (int i = threadIdx.x; i < NB; i += 256)
            __hip_atomic_store(flags + i * 32, gen, __ATOMIC_RELEASE, __HIP_MEMORY_SCOPE_AGENT);
    } else if (threadIdx.x == 0) {
        while (__hip_atomic_load(flags + bid * 32, __ATOMIC_ACQUIRE, __HIP_MEMORY_SCOPE_AGENT) < gen)
            __builtin_amdgcn_s_sleep(4);
    }
    __syncthreads();
    __threadfence();
}

// ---- 64x64 MFMA GEMM tile: C[bm:+64, bn:+64] = A(M,K) @ W(N,K)^T ----
__device__ __forceinline__ void gemm_tile(
    const float* __restrict__ A, const __bf16* __restrict__ W,
    float* __restrict__ C, const float* __restrict__ resid,
    int K, int N, int Lb, int tr, int bm, int bn,
    __bf16* sA, __bf16* sW)
{
    const int tid = threadIdx.x;
    const int lane = tid & 63, wv = tid >> 6;
    const int m_off = (wv & 1) * 32, n_off = (wv >> 1) * 32;
    const int fr = lane & 15, fq = lane >> 4;
    f32x4 acc[2][2] = {};

    for (int k0 = 0; k0 < K; k0 += 64) {
#pragma unroll
        for (int i = 0; i < 2; ++i) {
            const int cid = i * 256 + tid;
            const int row = cid >> 3, kc = cid & 7;
            const int slot = kc ^ (row & 7);
            const float* sa = A + (size_t)(bm + row) * K + k0 + kc * 8;
            f32x4 v0 = *(const f32x4*)sa;
            f32x4 v1 = *(const f32x4*)(sa + 4);
            bf16x8 ab;
#pragma unroll
            for (int j = 0; j < 4; ++j) { ab[j] = (__bf16)v0[j]; ab[4 + j] = (__bf16)v1[j]; }
            *(bf16x8*)&sA[row * 64 + slot * 8] = ab;
            *(bf16x8*)&sW[row * 64 + slot * 8] =
                *(const bf16x8*)(W + (size_t)(bn + row) * K + k0 + kc * 8);
        }
        __syncthreads();
#pragma unroll
        for (int ks = 0; ks < 2; ++ks) {
            const int kc = ks * 4 + fq;
            const int r0 = m_off + fr, r1 = m_off + 16 + fr;
            const int c0 = n_off + fr, c1 = n_off + 16 + fr;
            bf16x8 a0 = *(const bf16x8*)&sA[r0 * 64 + (kc ^ (r0 & 7)) * 8];
            bf16x8 a1 = *(const bf16x8*)&sA[r1 * 64 + (kc ^ (r1 & 7)) * 8];
            bf16x8 b0 = *(const bf16x8*)&sW[c0 * 64 + (kc ^ (c0 & 7)) * 8];
            bf16x8 b1 = *(const bf16x8*)&sW[c1 * 64 + (kc ^ (c1 & 7)) * 8];
            acc[0][0] = __builtin_amdgcn_mfma_f32_16x16x32_bf16(a0, b0, acc[0][0], 0, 0, 0);
            acc[0][1] = __builtin_amdgcn_mfma_f32_16x16x32_bf16(a0, b1, acc[0][1], 0, 0, 0);
            acc[1][0] = __builtin_amdgcn_mfma_f32_16x16x32_bf16(a1, b0, acc[1][0], 0, 0, 0);
            acc[1][1] = __builtin_amdgcn_mfma_f32_16x16x32_bf16(a1, b1, acc[1][1], 0, 0, 0);
        }
        __syncthreads();
    }
    if (!tr) {
#pragma unroll
        for (int i = 0; i < 2; ++i)
#pragma unroll
            for (int j = 0; j < 2; ++j)
#pragma unroll
                for (int r = 0; r < 4; ++r)
                    C[(size_t)(bm + m_off + i * 16 + fq * 4 + r) * N
                      + bn + n_off + j * 16 + fr] = acc[i][j][r];
    } else {
#pragma unroll
        for (int i = 0; i < 2; ++i)
#pragma unroll
            for (int j = 0; j < 2; ++j) {
                const int gn = bn + n_off + j * 16 + fr;
#pragma unroll
                for (int r = 0; r < 4; ++r) {
                    const int gm = bm + m_off + i * 16 + fq * 4 + r;
                    const int b = gm / Lb, t = gm - b * Lb;
                    const size_t o = ((size_t)(b * N + gn)) * Lb + t;
                    C[o] = acc[i][j][r] + (resid ? resid[o] : 0.f);
                }
            }
    }
}

__global__ __launch_bounds__(256)
void mega(MegaP p)
{
    __shared__ __bf16 sA[64 * 64];
    __shared__ __bf16 sW[64 * 64];
    const int tid = threadIdx.x;
    const int bid = blockIdx.x;
    const int gtid = bid * 256 + tid;
    unsigned gen = 0;

    // ---------------- phase 0: weight conversions ----------------
    {
        int tot = 0;
#pragma unroll
        for (int sgm = 0; sgm < 5; ++sgm) tot += p.cn[sgm];
        const int nvec = tot / 4;
        for (int i = gtid; i < nvec; i += NB * 256) {
            int idx = i * 4, sgm = 0, off = idx;
            while (off >= p.cn[sgm]) { off -= p.cn[sgm]; ++sgm; }
            f32x4 v = *(const f32x4*)(p.cs[sgm] + off);
            bf16x4 o;
#pragma unroll
            for (int j = 0; j < 4; ++j) o[j] = (__bf16)v[j];
            *(bf16x4*)(p.cd[sgm] + off) = o;
        }
        for (int i = gtid; i < 2 * 64 * 512; i += NB * 256) {
            const int c = i & 511, r = (i >> 9) & 63, l = i >> 15;
            float v = (r < 48) ? p.xpb[((size_t)l * 48 + r) * 512 + c] : 0.f;
            p.xpb_d[i] = (__bf16)v;
        }
    }
    gbar(p.bar, ++gen);

    for (int k = 0; k < 4; ++k) {
        const LayerP L = p.L[k];
        const int M = L.M, DM = L.DM, DI = L.DI, R = L.R, P = L.P, KS = L.KS, Lb = L.Lb;
        const int N2 = 2 * DI;

        // ---------------- in_proj: xz = src @ w_in^T ----------------
        {
            const int ncols = N2 / 64;
            const int nj = (M / 64) * ncols;
            for (int j = bid; j < nj; j += NB)
                gemm_tile(L.src, L.w_in, p.xz, nullptr, DM, N2, Lb, 0,
                          (j / ncols) * 64, (j % ncols) * 64, sA, sW);
        }
        gbar(p.bar, ++gen);

        // ------- fused conv+SiLU + split-K x_proj partials -> pk[ks][M][64] -------
        {
            const int nstripe = M / 64;
            const int nj = KS * nstripe;
            const int KC = DI / KS;
            for (int j = bid; j < nj; j += NB) {
                const int ks_ = j % KS, stripe = j / KS;
                const int bm = stripe * 64;
                const int kb = ks_ * KC;
                const int lane = tid & 63, wv = tid >> 6;
                const int m_off = (wv & 1) * 32, n_off = (wv >> 1) * 32;
                const int fr = lane & 15, fq = lane >> 4;
                const int b = bm / Lb;
                const int tbase = bm - b * Lb;
                f32x4 acc[2][2] = {};

                for (int k0 = kb; k0 < kb + KC; k0 += 64) {
#pragma unroll
                    for (int i = 0; i < 2; ++i) {
                        const int cid = i * 256 + tid;
                        const int row = cid >> 3, kc = cid & 7;
                        const int slot = kc ^ (row & 7);
                        const int d0 = k0 + kc * 8;
                        const int t = tbase + row;
                        f32x4 a0 = *(const f32x4*)&L.convb[d0];
                        f32x4 a1 = *(const f32x4*)&L.convb[d0 + 4];
                        f32x4 wc[8];
#pragma unroll
                        for (int cch = 0; cch < 8; ++cch)
                            wc[cch] = *(const f32x4*)&L.convw[(size_t)(d0 + cch) * 4];
#pragma unroll
                        for (int jj = 0; jj < 4; ++jj) {
                            const int tt = t - 3 + jj;
                            if (tt >= 0) {
                                const float* src = p.xz + (size_t)(b * Lb + tt) * N2 + d0;
                                f32x4 v0 = *(const f32x4*)src;
                                f32x4 v1 = *(const f32x4*)(src + 4);
#pragma unroll
                                for (int cch = 0; cch < 4; ++cch) {
                                    a0[cch] = fmaf(wc[cch][jj], v0[cch], a0[cch]);
                                    a1[cch] = fmaf(wc[4 + cch][jj], v1[cch], a1[cch]);
                                }
                            }
                        }
                        f32x4 r0v, r1v; bf16x8 ab;
#pragma unroll
                        for (int cch = 0; cch < 4; ++cch) {
                            const float u0 = a0[cch], u1 = a1[cch];
                            const float s0 = u0 / (1.f + __expf(-u0));
                            const float s1 = u1 / (1.f + __expf(-u1));
                            r0v[cch] = s0; r1v[cch] = s1;
                            ab[cch] = (__bf16)s0; ab[4 + cch] = (__bf16)s1;
                        }
                        const size_t mrow = (size_t)(bm + row);
                        *(f32x4*)&p.xi[mrow * DI + d0] = r0v;
                        *(f32x4*)&p.xi[mrow * DI + d0 + 4] = r1v;
                        *(bf16x8*)&sA[row * 64 + slot * 8] = ab;
                        *(bf16x8*)&sW[row * 64 + slot * 8] =
                            *(const bf16x8*)(L.w_xp + (size_t)row * DI + k0 + kc * 8);
                    }
                    __syncthreads();
#pragma unroll
                    for (int ksu = 0; ksu < 2; ++ksu) {
                        const int kc = ksu * 4 + fq;
                        const int r0 = m_off + fr, r1 = m_off + 16 + fr;
                        const int c0 = n_off + fr, c1 = n_off + 16 + fr;
                        bf16x8 a0 = *(const bf16x8*)&sA[r0 * 64 + (kc ^ (r0 & 7)) * 8];
                        bf16x8 a1 = *(const bf16x8*)&sA[r1 * 64 + (kc ^ (r1 & 7)) * 8];
                        bf16x8 b0 = *(const bf16x8*)&sW[c0 * 64 + (kc ^ (c0 & 7)) * 8];
                        bf16x8 b1 = *(const bf16x8*)&sW[c1 * 64 + (kc ^ (c1 & 7)) * 8];
                        acc[0][0] = __builtin_amdgcn_mfma_f32_16x16x32_bf16(a0, b0, acc[0][0], 0, 0, 0);
                        acc[0][1] = __builtin_amdgcn_mfma_f32_16x16x32_bf16(a0, b1, acc[0][1], 0, 0, 0);
                        acc[1][0] = __builtin_amdgcn_mfma_f32_16x16x32_bf16(a1, b0, acc[1][0], 0, 0, 0);
                        acc[1][1] = __builtin_amdgcn_mfma_f32_16x16x32_bf16(a1, b1, acc[1][1], 0, 0, 0);
                    }
                    __syncthreads();
                }
                float* out = p.pk + (size_t)ks_ * M * 64;
#pragma unroll
                for (int i = 0; i < 2; ++i)
#pragma unroll
                    for (int jj = 0; jj < 2; ++jj)
#pragma unroll
                        for (int r = 0; r < 4; ++r)
                            out[(size_t)(bm + m_off + i * 16 + fq * 4 + r) * 64
                                + n_off + jj * 16 + fr] = acc[i][jj][r];
            }
        }
        gbar(p.bar, ++gen);

        // ------- xp_finish: reduce partials -> xdbl f32; dt = softplus(xdbl@dtw^T+b) -------
        {
            float* sfin = (float*)sA;
            const int nj = M / 4;
            const int rl = tid >> 6, lane = tid & 63;
            for (int j = bid; j < nj; j += NB) {
                const int m = j * 4 + rl;
                float v = 0.f;
                for (int ks_ = 0; ks_ < KS; ++ks_)
                    v += p.pk[(size_t)ks_ * M * 64 + (size_t)m * 64 + lane];
                p.xdbl[(size_t)m * 64 + lane] = v;
                sfin[rl * 64 + lane] = v;
                __syncthreads();
                const int per = DI / 64;
                for (int o = 0; o < per; ++o) {
                    const int d = lane + o * 64;
                    const float* wr = L.dtw + (size_t)d * R;
                    float a2 = L.dtb[d];
                    for (int r = 0; r < R; ++r) a2 = fmaf(sfin[rl * 64 + r], wr[r], a2);
                    p.dtbuf[(size_t)m * DI + d] = fmaxf(a2, 0.f) + log1pf(__expf(-fabsf(a2)));
                }
                __syncthreads();
            }
        }
        gbar(p.bar, ++gen);

        // ---------------- scan phase 1 ----------------
        {
            const int s = tid & 15, dl = tid >> 4;
            const int nDB = DI >> 4, cpb = P * nDB;
            const int nj = 2 * cpb;
            for (int j = bid; j < nj; j += NB) {
                const int b = j / cpb, rem = j % cpb, c = rem / nDB;
                const int d = (rem % nDB) * 16 + dl;
                const float Av = -__expf(L.Alog[(size_t)d * 16 + s]);
                float h = 0.f, sdt = 0.f;
                const size_t rowbase = (size_t)b * Lb + c * 32;
#pragma unroll 4
                for (int t = 0; t < 32; ++t) {
                    const size_t m = rowbase + t;
                    const float dtv = p.dtbuf[m * DI + d];
                    const float xv  = p.xi[m * DI + d];
                    const float Bv  = p.xdbl[m * 64 + R + s];
                    h = fmaf(__expf(dtv * Av), h, dtv * Bv * xv);
                    sdt += dtv;
                }
                const size_t o = ((size_t)(b * P + c) * DI + d) * 16 + s;
                p.wsA[o] = __expf(sdt * Av);
                p.wsB[o] = h;
            }
        }
        gbar(p.bar, ++gen);

        // ---------------- scan phases 2+3 ----------------
        {
            const int s = tid & 15, dl = tid >> 4;
            const int nDB = DI >> 4, cpb = P * nDB;
            const int nj = 2 * cpb;
            for (int j = bid; j < nj; j += NB) {
                const int b = j / cpb, rem = j % cpb, c = rem / nDB;
                const int d = (rem % nDB) * 16 + dl;
                const float Av = -__expf(L.Alog[(size_t)d * 16 + s]);
                const float Dv = L.Dp[d];
                float h = 0.f;
                for (int cc = 0; cc < c; ++cc) {
                    const size_t oc = ((size_t)(b * P + cc) * DI + d) * 16 + s;
                    h = fmaf(p.wsA[oc], h, p.wsB[oc]);
                }
                const size_t rowbase = (size_t)b * Lb + c * 32;
#pragma unroll 2
                for (int t = 0; t < 32; ++t) {
                    const size_t m = rowbase + t;
                    const float dtv = p.dtbuf[m * DI + d];
                    const float xv  = p.xi[m * DI + d];
                    const float Bv  = p.xdbl[m * 64 + R + s];
                    const float Cv  = p.xdbl[m * 64 + R + 16 + s];
                    h = fmaf(__expf(dtv * Av), h, dtv * Bv * xv);
                    float pp = h * Cv;
                    pp += __shfl_xor(pp, 1, 16);
                    pp += __shfl_xor(pp, 2, 16);
                    pp += __shfl_xor(pp, 4, 16);
                    pp += __shfl_xor(pp, 8, 16);
                    if (s == 0) {
                        const float zv = p.xz[m * (size_t)N2 + DI + d];
                        const float sig = __fdividef(zv, 1.f + __expf(-zv));
                        p.y[m * DI + d] = (pp + Dv * xv) * sig;
                    }
                }
            }
        }
        gbar(p.bar, ++gen);

        // ---------------- out_proj ----------------
        {
            const int ncols = DM / 64;
            const int nj = (M / 64) * ncols;
            for (int j = bid; j < nj; j += NB)
                gemm_tile(p.y, L.w_out, L.dst, L.resid, DI, DM, Lb, L.tr,
                          (j / ncols) * 64, (j % ncols) * 64, sA, sW);
        }
        if (k < 3) gbar(p.bar, ++gen);
    }
}

extern "C" void kernel_launch(void* const* d_in, const int* in_sizes, int n_in,
                              void* d_out, int out_size, void* d_ws, size_t ws_size,
                              hipStream_t stream)
{
    const float* x       = (const float*)d_in[0];
    const float* a_in_w  = (const float*)d_in[1];
    const float* a_convw = (const float*)d_in[2];
    const float* a_convb = (const float*)d_in[3];
    const float* a_xproj = (const float*)d_in[4];
    const float* a_dtw   = (const float*)d_in[5];
    const float* a_dtb   = (const float*)d_in[6];
    const float* a_Alog  = (const float*)d_in[7];
    const float* a_Dp    = (const float*)d_in[8];
    const float* a_outw  = (const float*)d_in[9];
    const float* b_in_w  = (const float*)d_in[10];
    const float* b_convw = (const float*)d_in[11];
    const float* b_convb = (const float*)d_in[12];
    const float* b_xproj = (const float*)d_in[13];
    const float* b_dtw   = (const float*)d_in[14];
    const float* b_dtb   = (const float*)d_in[15];
    const float* b_Alog  = (const float*)d_in[16];
    const float* b_Dp    = (const float*)d_in[17];
    const float* b_outw  = (const float*)d_in[18];

    float* ws = (float*)d_ws;
    unsigned* bar   = (unsigned*)ws;         // BAR_UINTS
    float* base     = ws + BAR_UINTS;
    float* buf_x    = base;                  // 262144
    float* buf_x2   = buf_x + 262144;        // 262144
    float* buf_xz   = buf_x2 + 262144;       // 1048576
    float* buf_xi   = buf_xz + 1048576;      // 524288
    float* buf_xd   = buf_xi + 524288;       // 65536
    float* buf_dt   = buf_xd + 65536;        // 524288
    float* buf_y    = buf_dt + 524288;       // 524288
    float* buf_pk   = buf_y + 524288;        // 262144
    float* buf_wsA  = buf_pk + 262144;       // 262144
    float* buf_wsB  = buf_wsA + 262144;      // 262144
    __bf16* wb       = (__bf16*)(buf_wsB + 262144);
    __bf16* wb_a_in  = wb;                   // 2097152
    __bf16* wb_a_out = wb_a_in + 2097152;    // 1048576
    __bf16* wb_b_in  = wb_a_out + 1048576;   // 524288
    __bf16* wb_b_out = wb_b_in + 524288;     // 262144
    __bf16* wb_xp_a  = wb_b_out + 262144;    // 131072 (2,64,1024)
    __bf16* wb_xp_b  = wb_xp_a + 131072;     // 65536  (2,64,512) padded

    MegaP p;
    p.bar = bar;
    p.xz = buf_xz; p.xi = buf_xi; p.xdbl = buf_xd; p.dtbuf = buf_dt;
    p.y = buf_y; p.pk = buf_pk; p.wsA = buf_wsA; p.wsB = buf_wsB;
    p.cs[0] = a_in_w;  p.cd[0] = wb_a_in;  p.cn[0] = 2097152;
    p.cs[1] = a_outw;  p.cd[1] = wb_a_out; p.cn[1] = 1048576;
    p.cs[2] = b_in_w;  p.cd[2] = wb_b_in;  p.cn[2] = 524288;
    p.cs[3] = b_outw;  p.cd[3] = wb_b_out; p.cn[3] = 262144;
    p.cs[4] = a_xproj; p.cd[4] = wb_xp_a;  p.cn[4] = 131072;
    p.xpb = b_xproj;   p.xpb_d = wb_xp_b;

    for (int k = 0; k < 2; ++k) {
        LayerP& L = p.L[k];
        L.M = 512; L.DM = 512; L.DI = 1024; L.R = 32; L.P = 8; L.KS = 8; L.Lb = 256;
        L.src = (k == 0) ? x : buf_x;
        L.w_in = wb_a_in + (size_t)k * 2 * 1024 * 512;
        L.convw = a_convw + (size_t)k * 1024 * 4;
        L.convb = a_convb + (size_t)k * 1024;
        L.w_xp = wb_xp_a + (size_t)k * 64 * 1024;
        L.dtw = a_dtw + (size_t)k * 1024 * 32;
        L.dtb = a_dtb + (size_t)k * 1024;
        L.Alog = a_Alog + (size_t)k * 1024 * 16;
        L.Dp = a_Dp + (size_t)k * 1024;
        L.w_out = wb_a_out + (size_t)k * 512 * 1024;
        L.dst = (k == 0) ? buf_x : buf_x2;
        L.resid = nullptr;
        L.tr = (k == 1) ? 1 : 0;
    }
    for (int k = 0; k < 2; ++k) {
        LayerP& L = p.L[2 + k];
        L.M = 1024; L.DM = 256; L.DI = 512; L.R = 16; L.P = 16; L.KS = 4; L.Lb = 512;
        L.src = (k == 0) ? buf_x2 : buf_x;
        L.w_in = wb_b_in + (size_t)k * 2 * 512 * 256;
        L.convw = b_convw + (size_t)k * 512 * 4;
        L.convb = b_convb + (size_t)k * 512;
        L.w_xp = wb_xp_b + (size_t)k * 64 * 512;
        L.dtw = b_dtw + (size_t)k * 512 * 16;
        L.dtb = b_dtb + (size_t)k * 512;
        L.Alog = b_Alog + (size_t)k * 512 * 16;
        L.Dp = b_Dp + (size_t)k * 512;
        L.w_out = wb_b_out + (size_t)k * 256 * 512;
        L.dst = (k == 0) ? buf_x : (float*)d_out;
        L.resid = (k == 1) ? x : nullptr;
        L.tr = (k == 1) ? 1 : 0;
    }

    hipMemsetAsync(bar, 0, BAR_UINTS * sizeof(unsigned), stream);
    mega<<<NB, 256, 0, stream>>>(p);
}

// Round 11
// 404.683 us; speedup vs baseline: 12.7716x; 12.7716x over previous
//
#include <hip/hip_runtime.h>
#include <cstdint>

typedef float f32x4 __attribute__((ext_vector_type(4)));
typedef __bf16 bf16x8 __attribute__((ext_vector_type(8)));
typedef __bf16 bf16x4 __attribute__((ext_vector_type(4)));

// Problem constants
// group a: M=512,  DM=512, DI=1024, R=32, P=8,  KS=8,  Lb=256
// group b: M=1024, DM=256, DI=512,  R=16, P=16, KS=4,  Lb=512
#define SCAN_TC 32

// ---------------- merged weight conversion ----------------
// 5 plain f32->bf16 segments (vec4) + padded xproj_b (2,48,512)->(2,64,512)
struct CvtP {
    const float* cs[5]; __bf16* cd[5]; int cn[5]; int nvec;
    const float* xpb; __bf16* xpb_d;
};

__global__ __launch_bounds__(256)
void cvt_all(CvtP p)
{
    const int idx = blockIdx.x * 256 + threadIdx.x;
    if (idx < p.nvec) {
        int off = idx * 4, sgm = 0;
        while (off >= p.cn[sgm]) { off -= p.cn[sgm]; ++sgm; }
        f32x4 v = *(const f32x4*)(p.cs[sgm] + off);
        bf16x4 o;
#pragma unroll
        for (int j = 0; j < 4; ++j) o[j] = (__bf16)v[j];
        *(bf16x4*)(p.cd[sgm] + off) = o;
    } else {
        const int i = idx - p.nvec;
        if (i < 2 * 64 * 512) {
            const int c = i & 511, r = (i >> 9) & 63, l = i >> 15;
            float v = (r < 48) ? p.xpb[((size_t)l * 48 + r) * 512 + c] : 0.f;
            p.xpb_d[i] = (__bf16)v;
        }
    }
}

// ---------------- MFMA GEMM: C(M,N) = A(M,K) @ W(N,K)^T ----------------
__global__ __launch_bounds__(256)
void gemm_bf16(const float* __restrict__ A, const __bf16* __restrict__ W,
               float* __restrict__ C, int M, int N, int K)
{
    __shared__ __bf16 sA[64 * 64];
    __shared__ __bf16 sW[64 * 64];
    const int tid = threadIdx.x;
    const int bm = blockIdx.y * 64, bn = blockIdx.x * 64;
    const int lane = tid & 63, wv = tid >> 6;
    const int m_off = (wv & 1) * 32, n_off = (wv >> 1) * 32;
    const int fr = lane & 15, fq = lane >> 4;
    f32x4 acc[2][2] = {};

    for (int k0 = 0; k0 < K; k0 += 64) {
#pragma unroll
        for (int i = 0; i < 2; ++i) {
            const int cid = i * 256 + tid;
            const int row = cid >> 3, kc = cid & 7;
            const int slot = kc ^ (row & 7);
            const float* sa = A + (size_t)(bm + row) * K + k0 + kc * 8;
            f32x4 v0 = *(const f32x4*)sa;
            f32x4 v1 = *(const f32x4*)(sa + 4);
            bf16x8 ab;
#pragma unroll
            for (int j = 0; j < 4; ++j) { ab[j] = (__bf16)v0[j]; ab[4 + j] = (__bf16)v1[j]; }
            *(bf16x8*)&sA[row * 64 + slot * 8] = ab;
            *(bf16x8*)&sW[row * 64 + slot * 8] =
                *(const bf16x8*)(W + (size_t)(bn + row) * K + k0 + kc * 8);
        }
        __syncthreads();
#pragma unroll
        for (int ks = 0; ks < 2; ++ks) {
            const int kc = ks * 4 + fq;
            const int r0 = m_off + fr, r1 = m_off + 16 + fr;
            const int c0 = n_off + fr, c1 = n_off + 16 + fr;
            bf16x8 a0 = *(const bf16x8*)&sA[r0 * 64 + (kc ^ (r0 & 7)) * 8];
            bf16x8 a1 = *(const bf16x8*)&sA[r1 * 64 + (kc ^ (r1 & 7)) * 8];
            bf16x8 b0 = *(const bf16x8*)&sW[c0 * 64 + (kc ^ (c0 & 7)) * 8];
            bf16x8 b1 = *(const bf16x8*)&sW[c1 * 64 + (kc ^ (c1 & 7)) * 8];
            acc[0][0] = __builtin_amdgcn_mfma_f32_16x16x32_bf16(a0, b0, acc[0][0], 0, 0, 0);
            acc[0][1] = __builtin_amdgcn_mfma_f32_16x16x32_bf16(a0, b1, acc[0][1], 0, 0, 0);
            acc[1][0] = __builtin_amdgcn_mfma_f32_16x16x32_bf16(a1, b0, acc[1][0], 0, 0, 0);
            acc[1][1] = __builtin_amdgcn_mfma_f32_16x16x32_bf16(a1, b1, acc[1][1], 0, 0, 0);
        }
        __syncthreads();
    }
#pragma unroll
    for (int i = 0; i < 2; ++i)
#pragma unroll
        for (int j = 0; j < 2; ++j)
#pragma unroll
            for (int r = 0; r < 4; ++r)
                C[(size_t)(bm + m_off + i * 16 + fq * 4 + r) * N
                  + bn + n_off + j * 16 + fr] = acc[i][j][r];
}

// ---- same GEMM, transposed store: dst[(b*N + col)*Lb + t] (+ optional resid) ----
__global__ __launch_bounds__(256)
void gemm_bf16_tr(const float* __restrict__ A, const __bf16* __restrict__ W,
                  float* __restrict__ dst, const float* __restrict__ resid,
                  int M, int N, int K, int Lb)
{
    __shared__ __bf16 sA[64 * 64];
    __shared__ __bf16 sW[64 * 64];
    const int tid = threadIdx.x;
    const int bm = blockIdx.y * 64, bn = blockIdx.x * 64;
    const int lane = tid & 63, wv = tid >> 6;
    const int m_off = (wv & 1) * 32, n_off = (wv >> 1) * 32;
    const int fr = lane & 15, fq = lane >> 4;
    f32x4 acc[2][2] = {};

    for (int k0 = 0; k0 < K; k0 += 64) {
#pragma unroll
        for (int i = 0; i < 2; ++i) {
            const int cid = i * 256 + tid;
            const int row = cid >> 3, kc = cid & 7;
            const int slot = kc ^ (row & 7);
            const float* sa = A + (size_t)(bm + row) * K + k0 + kc * 8;
            f32x4 v0 = *(const f32x4*)sa;
            f32x4 v1 = *(const f32x4*)(sa + 4);
            bf16x8 ab;
#pragma unroll
            for (int j = 0; j < 4; ++j) { ab[j] = (__bf16)v0[j]; ab[4 + j] = (__bf16)v1[j]; }
            *(bf16x8*)&sA[row * 64 + slot * 8] = ab;
            *(bf16x8*)&sW[row * 64 + slot * 8] =
                *(const bf16x8*)(W + (size_t)(bn + row) * K + k0 + kc * 8);
        }
        __syncthreads();
#pragma unroll
        for (int ks = 0; ks < 2; ++ks) {
            const int kc = ks * 4 + fq;
            const int r0 = m_off + fr, r1 = m_off + 16 + fr;
            const int c0 = n_off + fr, c1 = n_off + 16 + fr;
            bf16x8 a0 = *(const bf16x8*)&sA[r0 * 64 + (kc ^ (r0 & 7)) * 8];
            bf16x8 a1 = *(const bf16x8*)&sA[r1 * 64 + (kc ^ (r1 & 7)) * 8];
            bf16x8 b0 = *(const bf16x8*)&sW[c0 * 64 + (kc ^ (c0 & 7)) * 8];
            bf16x8 b1 = *(const bf16x8*)&sW[c1 * 64 + (kc ^ (c1 & 7)) * 8];
            acc[0][0] = __builtin_amdgcn_mfma_f32_16x16x32_bf16(a0, b0, acc[0][0], 0, 0, 0);
            acc[0][1] = __builtin_amdgcn_mfma_f32_16x16x32_bf16(a0, b1, acc[0][1], 0, 0, 0);
            acc[1][0] = __builtin_amdgcn_mfma_f32_16x16x32_bf16(a1, b0, acc[1][0], 0, 0, 0);
            acc[1][1] = __builtin_amdgcn_mfma_f32_16x16x32_bf16(a1, b1, acc[1][1], 0, 0, 0);
        }
        __syncthreads();
    }
#pragma unroll
    for (int i = 0; i < 2; ++i)
#pragma unroll
        for (int j = 0; j < 2; ++j) {
            const int gn = bn + n_off + j * 16 + fr;
#pragma unroll
            for (int r = 0; r < 4; ++r) {
                const int gm = bm + m_off + i * 16 + fq * 4 + r;
                const int b = gm / Lb, t = gm - b * Lb;
                const size_t o = ((size_t)(b * N + gn)) * Lb + t;
                dst[o] = acc[i][j][r] + (resid ? resid[o] : 0.f);
            }
        }
}

// ------- fused conv+SiLU + split-K x_proj partials + last-block stripe reduce -------
// grid (KS, M/64). pbuf[ks][M][64]; last block per stripe reduces -> xdbl (M x 64 f32).
// scnt: per-stripe counters (32-uint stride), monotonically increasing across the
// 4 invocations in one launch; cbase = sum of previous invocations' KS.
__global__ __launch_bounds__(256)
void fused_xp(const float* __restrict__ xz, const float* __restrict__ conv_w,
              const float* __restrict__ conv_b, const __bf16* __restrict__ W,
              float* __restrict__ xi_out, float* __restrict__ pbuf,
              float* __restrict__ xdbl, unsigned* __restrict__ scnt, unsigned cbase,
              int M, int K, int KC, int Lb)
{
    __shared__ __bf16 sA[64 * 64];
    __shared__ __bf16 sW[64 * 64];
    __shared__ unsigned s_last;
    const int tid = threadIdx.x;
    const int bm = blockIdx.y * 64;
    const int kb = blockIdx.x * KC;
    const int KS = gridDim.x;
    const int lane = tid & 63, wv = tid >> 6;
    const int m_off = (wv & 1) * 32, n_off = (wv >> 1) * 32;
    const int fr = lane & 15, fq = lane >> 4;
    const int DI = K;
    const int b = bm / Lb;
    const int tbase = bm - b * Lb;
    f32x4 acc[2][2] = {};

    for (int k0 = kb; k0 < kb + KC; k0 += 64) {
#pragma unroll
        for (int i = 0; i < 2; ++i) {
            const int cid = i * 256 + tid;
            const int row = cid >> 3, kc = cid & 7;
            const int slot = kc ^ (row & 7);
            const int d0 = k0 + kc * 8;
            const int t = tbase + row;
            f32x4 a0 = *(const f32x4*)&conv_b[d0];
            f32x4 a1 = *(const f32x4*)&conv_b[d0 + 4];
            f32x4 wc[8];
#pragma unroll
            for (int cch = 0; cch < 8; ++cch)
                wc[cch] = *(const f32x4*)&conv_w[(size_t)(d0 + cch) * 4];
#pragma unroll
            for (int jj = 0; jj < 4; ++jj) {
                const int tt = t - 3 + jj;
                if (tt >= 0) {
                    const float* src = xz + (size_t)(b * Lb + tt) * (2 * DI) + d0;
                    f32x4 v0 = *(const f32x4*)src;
                    f32x4 v1 = *(const f32x4*)(src + 4);
#pragma unroll
                    for (int cch = 0; cch < 4; ++cch) {
                        a0[cch] = fmaf(wc[cch][jj], v0[cch], a0[cch]);
                        a1[cch] = fmaf(wc[4 + cch][jj], v1[cch], a1[cch]);
                    }
                }
            }
            f32x4 r0v, r1v; bf16x8 ab;
#pragma unroll
            for (int cch = 0; cch < 4; ++cch) {
                const float u0 = a0[cch], u1 = a1[cch];
                const float s0 = u0 / (1.f + __expf(-u0));
                const float s1 = u1 / (1.f + __expf(-u1));
                r0v[cch] = s0; r1v[cch] = s1;
                ab[cch] = (__bf16)s0; ab[4 + cch] = (__bf16)s1;
            }
            const size_t mrow = (size_t)(bm + row);
            *(f32x4*)&xi_out[mrow * DI + d0] = r0v;
            *(f32x4*)&xi_out[mrow * DI + d0 + 4] = r1v;
            *(bf16x8*)&sA[row * 64 + slot * 8] = ab;
            *(bf16x8*)&sW[row * 64 + slot * 8] =
                *(const bf16x8*)(W + (size_t)row * K + k0 + kc * 8);
        }
        __syncthreads();
#pragma unroll
        for (int ksu = 0; ksu < 2; ++ksu) {
            const int kc = ksu * 4 + fq;
            const int r0 = m_off + fr, r1 = m_off + 16 + fr;
            const int c0 = n_off + fr, c1 = n_off + 16 + fr;
            bf16x8 a0 = *(const bf16x8*)&sA[r0 * 64 + (kc ^ (r0 & 7)) * 8];
            bf16x8 a1 = *(const bf16x8*)&sA[r1 * 64 + (kc ^ (r1 & 7)) * 8];
            bf16x8 b0 = *(const bf16x8*)&sW[c0 * 64 + (kc ^ (c0 & 7)) * 8];
            bf16x8 b1 = *(const bf16x8*)&sW[c1 * 64 + (kc ^ (c1 & 7)) * 8];
            acc[0][0] = __builtin_amdgcn_mfma_f32_16x16x32_bf16(a0, b0, acc[0][0], 0, 0, 0);
            acc[0][1] = __builtin_amdgcn_mfma_f32_16x16x32_bf16(a0, b1, acc[0][1], 0, 0, 0);
            acc[1][0] = __builtin_amdgcn_mfma_f32_16x16x32_bf16(a1, b0, acc[1][0], 0, 0, 0);
            acc[1][1] = __builtin_amdgcn_mfma_f32_16x16x32_bf16(a1, b1, acc[1][1], 0, 0, 0);
        }
        __syncthreads();
    }
    float* out = pbuf + (size_t)blockIdx.x * M * 64;
#pragma unroll
    for (int i = 0; i < 2; ++i)
#pragma unroll
        for (int jj = 0; jj < 2; ++jj)
#pragma unroll
            for (int r = 0; r < 4; ++r)
                out[(size_t)(bm + m_off + i * 16 + fq * 4 + r) * 64
                    + n_off + jj * 16 + fr] = acc[i][jj][r];

    // ---- last block per stripe reduces partials -> xdbl ----
    __threadfence();
    __syncthreads();
    if (tid == 0) {
        unsigned old = __hip_atomic_fetch_add(scnt + blockIdx.y * 32, 1u,
                                              __ATOMIC_ACQ_REL, __HIP_MEMORY_SCOPE_AGENT);
        s_last = (old == cbase + (unsigned)KS - 1u) ? 1u : 0u;
    }
    __syncthreads();
    if (s_last) {
#pragma unroll
        for (int e = 0; e < 16; ++e) {
            const int idx = e * 256 + tid;
            const int row = idx >> 6, col = idx & 63;
            float v = 0.f;
            for (int ks_ = 0; ks_ < KS; ++ks_)
                v += pbuf[(size_t)ks_ * M * 64 + (size_t)(bm + row) * 64 + col];
            xdbl[(size_t)(bm + row) * 64 + col] = v;
        }
    }
}

// ---------------- scan phase 1 (stage xdbl, dt in f32 LDS) ----------------
__global__ __launch_bounds__(256)
void scan_p1(const float* __restrict__ xi, const float* __restrict__ xdbl,
             const float* __restrict__ dtw, const float* __restrict__ dtb,
             const float* __restrict__ A_log,
             float* __restrict__ wsA, float* __restrict__ wsB,
             int Bb, int Lb, int DI, int R, int P)
{
    __shared__ float s_xd[SCAN_TC][64];
    __shared__ float s_dt[SCAN_TC][16];
    __shared__ float s_xi[SCAN_TC][16];
    __shared__ float s_w[16 * 33];
    __shared__ float s_db[16];
    const int tid = threadIdx.x;
    const int s = tid & 15, dl = tid >> 4;
    const int nDB = DI / 16;
    const int cpb = P * nDB;
    const int b = blockIdx.x / cpb;
    const int rem = blockIdx.x % cpb;
    const int c = rem / nDB;
    const int d0 = (rem % nDB) * 16;
    const int d = d0 + dl;
    const size_t rowbase = (size_t)b * Lb + (size_t)c * SCAN_TC;

    for (int idx = tid; idx < 16 * R; idx += 256)
        s_w[(idx / R) * 33 + (idx % R)] = dtw[(size_t)(d0 + idx / R) * R + idx % R];
    if (tid < 16) s_db[tid] = dtb[d0 + tid];
#pragma unroll
    for (int i = 0; i < 8; ++i) {
        const int e = i * 256 + tid;
        const int tt = e >> 6, col = e & 63;
        s_xd[tt][col] = xdbl[(rowbase + tt) * 64 + col];
    }
#pragma unroll
    for (int i = 0; i < 2; ++i) {
        const int e = i * 256 + tid;
        const int tt = e >> 4, dd = e & 15;
        s_xi[tt][dd] = xi[(rowbase + tt) * DI + d0 + dd];
    }
    __syncthreads();
#pragma unroll
    for (int i = 0; i < 2; ++i) {
        const int pr = i * 256 + tid;
        const int tt = pr >> 4, dd = pr & 15;
        float v = s_db[dd];
        for (int r = 0; r < R; ++r) v = fmaf(s_xd[tt][r], s_w[dd * 33 + r], v);
        s_dt[tt][dd] = fmaxf(v, 0.f) + log1pf(__expf(-fabsf(v)));
    }
    __syncthreads();
    const float A = -__expf(A_log[(size_t)d * 16 + s]);
    float h = 0.f, sdt = 0.f;
#pragma unroll 4
    for (int t = 0; t < SCAN_TC; ++t) {
        const float dtv = s_dt[t][dl];
        const float xv  = s_xi[t][dl];
        const float Bv  = s_xd[t][R + s];
        h = fmaf(__expf(dtv * A), h, dtv * Bv * xv);
        sdt += dtv;
    }
    const size_t o = ((size_t)(b * P + c) * DI + d) * 16 + s;
    wsA[o] = __expf(sdt * A);
    wsB[o] = h;
}

// ---------------- scan phases 2+3 ----------------
__global__ __launch_bounds__(256)
void scan_p23(const float* __restrict__ xi, const float* __restrict__ xdbl,
              const float* __restrict__ xz,
              const float* __restrict__ dtw, const float* __restrict__ dtb,
              const float* __restrict__ A_log, const float* __restrict__ Dp,
              const float* __restrict__ wsA, const float* __restrict__ wsB,
              float* __restrict__ y,
              int Bb, int Lb, int DI, int R, int P)
{
    __shared__ float s_xd[SCAN_TC][64];
    __shared__ float s_dt[SCAN_TC][16];
    __shared__ float s_xi[SCAN_TC][16];
    __shared__ float s_z [SCAN_TC][16];
    __shared__ float s_w[16 * 33];
    __shared__ float s_db[16];
    const int tid = threadIdx.x;
    const int s = tid & 15, dl = tid >> 4;
    const int nDB = DI / 16;
    const int cpb = P * nDB;
    const int b = blockIdx.x / cpb;
    const int rem = blockIdx.x % cpb;
    const int c = rem / nDB;
    const int d0 = (rem % nDB) * 16;
    const int d = d0 + dl;
    const size_t rowbase = (size_t)b * Lb + (size_t)c * SCAN_TC;

    for (int idx = tid; idx < 16 * R; idx += 256)
        s_w[(idx / R) * 33 + (idx % R)] = dtw[(size_t)(d0 + idx / R) * R + idx % R];
    if (tid < 16) s_db[tid] = dtb[d0 + tid];
#pragma unroll
    for (int i = 0; i < 8; ++i) {
        const int e = i * 256 + tid;
        const int tt = e >> 6, col = e & 63;
        s_xd[tt][col] = xdbl[(rowbase + tt) * 64 + col];
    }
#pragma unroll
    for (int i = 0; i < 2; ++i) {
        const int e = i * 256 + tid;
        const int tt = e >> 4, dd = e & 15;
        s_xi[tt][dd] = xi[(rowbase + tt) * DI + d0 + dd];
        s_z [tt][dd] = xz[(rowbase + tt) * (size_t)(2 * DI) + DI + d0 + dd];
    }
    __syncthreads();
#pragma unroll
    for (int i = 0; i < 2; ++i) {
        const int pr = i * 256 + tid;
        const int tt = pr >> 4, dd = pr & 15;
        float v = s_db[dd];
        for (int r = 0; r < R; ++r) v = fmaf(s_xd[tt][r], s_w[dd * 33 + r], v);
        s_dt[tt][dd] = fmaxf(v, 0.f) + log1pf(__expf(-fabsf(v)));
    }
    __syncthreads();
    const float A = -__expf(A_log[(size_t)d * 16 + s]);
    const float Dv = Dp[d];

    float h = 0.f;
    for (int cc = 0; cc < c; ++cc) {
        const size_t oc = ((size_t)(b * P + cc) * DI + d) * 16 + s;
        h = fmaf(wsA[oc], h, wsB[oc]);
    }
#pragma unroll 2
    for (int t = 0; t < SCAN_TC; ++t) {
        const float dtv = s_dt[t][dl];
        const float xv  = s_xi[t][dl];
        const float Bv  = s_xd[t][R + s];
        const float Cv  = s_xd[t][R + 16 + s];
        h = fmaf(__expf(dtv * A), h, dtv * Bv * xv);
        float p = h * Cv;
        p += __shfl_xor(p, 1, 16);
        p += __shfl_xor(p, 2, 16);
        p += __shfl_xor(p, 4, 16);
        p += __shfl_xor(p, 8, 16);
        if (s == 0) {
            const float zv = s_z[t][dl];
            const float sig = __fdividef(zv, 1.f + __expf(-zv));
            y[(rowbase + t) * DI + d] = (p + Dv * xv) * sig;
        }
    }
}

extern "C" void kernel_launch(void* const* d_in, const int* in_sizes, int n_in,
                              void* d_out, int out_size, void* d_ws, size_t ws_size,
                              hipStream_t stream)
{
    const float* x       = (const float*)d_in[0];
    const float* a_in_w  = (const float*)d_in[1];
    const float* a_convw = (const float*)d_in[2];
    const float* a_convb = (const float*)d_in[3];
    const float* a_xproj = (const float*)d_in[4];
    const float* a_dtw   = (const float*)d_in[5];
    const float* a_dtb   = (const float*)d_in[6];
    const float* a_Alog  = (const float*)d_in[7];
    const float* a_Dp    = (const float*)d_in[8];
    const float* a_outw  = (const float*)d_in[9];
    const float* b_in_w  = (const float*)d_in[10];
    const float* b_convw = (const float*)d_in[11];
    const float* b_convb = (const float*)d_in[12];
    const float* b_xproj = (const float*)d_in[13];
    const float* b_dtw   = (const float*)d_in[14];
    const float* b_dtb   = (const float*)d_in[15];
    const float* b_Alog  = (const float*)d_in[16];
    const float* b_Dp    = (const float*)d_in[17];
    const float* b_outw  = (const float*)d_in[18];

    float* ws = (float*)d_ws;
    unsigned* scnt  = (unsigned*)ws;       // 1024 uints (16 stripes x 32, spare)
    float* base     = ws + 1024;
    float* buf_x    = base;                // 262144
    float* buf_x2   = buf_x + 262144;      // 262144
    float* buf_xz   = buf_x2 + 262144;     // 1048576
    float* buf_xi   = buf_xz + 1048576;    // 524288
    float* buf_xd   = buf_xi + 524288;     // 65536
    float* buf_y    = buf_xd + 65536;      // 524288
    float* buf_pk   = buf_y + 524288;      // 262144
    float* buf_wsA  = buf_pk + 262144;     // 262144
    float* buf_wsB  = buf_wsA + 262144;    // 262144
    __bf16* wb       = (__bf16*)(buf_wsB + 262144);
    __bf16* wb_a_in  = wb;                 // 2097152
    __bf16* wb_a_out = wb_a_in + 2097152;  // 1048576
    __bf16* wb_b_in  = wb_a_out + 1048576; // 524288
    __bf16* wb_b_out = wb_b_in + 524288;   // 262144
    __bf16* wb_xp_a  = wb_b_out + 262144;  // 131072 (2,64,1024)
    __bf16* wb_xp_b  = wb_xp_a + 131072;   // 65536  (2,64,512) padded

    // zero the stripe counters (captured in graph, deterministic per replay)
    hipMemsetAsync(scnt, 0, 1024 * sizeof(unsigned), stream);

    // merged weight conversion
    {
        CvtP cp;
        cp.cs[0] = a_in_w;  cp.cd[0] = wb_a_in;  cp.cn[0] = 2097152;
        cp.cs[1] = a_outw;  cp.cd[1] = wb_a_out; cp.cn[1] = 1048576;
        cp.cs[2] = b_in_w;  cp.cd[2] = wb_b_in;  cp.cn[2] = 524288;
        cp.cs[3] = b_outw;  cp.cd[3] = wb_b_out; cp.cn[3] = 262144;
        cp.cs[4] = a_xproj; cp.cd[4] = wb_xp_a;  cp.cn[4] = 131072;
        cp.nvec = (2097152 + 1048576 + 524288 + 262144 + 131072) / 4;
        cp.xpb = b_xproj; cp.xpb_d = wb_xp_b;
        const int nthr = cp.nvec + 2 * 64 * 512;
        cvt_all<<<(nthr + 255) / 256, 256, 0, stream>>>(cp);
    }

    unsigned cbase = 0;
    // -------- group a: Bb=2, Lb=256, DM=512, DI=1024, R=32, P=8, KS=8 --------
    for (int k = 0; k < 2; ++k) {
        const int Bb = 2, Lb = 256, DM = 512, DI = 1024, R = 32, P = 8, KS = 8;
        const int M = Bb * Lb;
        const float* src = (k == 0) ? x : buf_x;
        gemm_bf16<<<dim3(2 * DI / 64, M / 64), 256, 0, stream>>>(
            src, wb_a_in + (size_t)k * 2 * DI * DM, buf_xz, M, 2 * DI, DM);
        fused_xp<<<dim3(KS, M / 64), 256, 0, stream>>>(
            buf_xz, a_convw + (size_t)k * DI * 4, a_convb + (size_t)k * DI,
            wb_xp_a + (size_t)k * 64 * DI, buf_xi, buf_pk, buf_xd, scnt, cbase,
            M, DI, DI / KS, Lb);
        cbase += KS;
        scan_p1<<<Bb * P * DI / 16, 256, 0, stream>>>(
            buf_xi, buf_xd, a_dtw + (size_t)k * DI * R, a_dtb + (size_t)k * DI,
            a_Alog + (size_t)k * DI * 16, buf_wsA, buf_wsB, Bb, Lb, DI, R, P);
        scan_p23<<<Bb * P * DI / 16, 256, 0, stream>>>(
            buf_xi, buf_xd, buf_xz, a_dtw + (size_t)k * DI * R, a_dtb + (size_t)k * DI,
            a_Alog + (size_t)k * DI * 16, a_Dp + (size_t)k * DI,
            buf_wsA, buf_wsB, buf_y, Bb, Lb, DI, R, P);
        if (k == 0)
            gemm_bf16<<<dim3(DM / 64, M / 64), 256, 0, stream>>>(
                buf_y, wb_a_out + (size_t)k * DM * DI, buf_x, M, DM, DI);
        else
            gemm_bf16_tr<<<dim3(DM / 64, M / 64), 256, 0, stream>>>(
                buf_y, wb_a_out + (size_t)k * DM * DI, buf_x2, nullptr, M, DM, DI, Lb);
    }

    // -------- group b: Bb=2, Lb=512, DM=256, DI=512, R=16, P=16, KS=4 --------
    for (int k = 0; k < 2; ++k) {
        const int Bb = 2, Lb = 512, DM = 256, DI = 512, R = 16, P = 16, KS = 4;
        const int M = Bb * Lb;
        const float* src = (k == 0) ? buf_x2 : buf_x;
        gemm_bf16<<<dim3(2 * DI / 64, M / 64), 256, 0, stream>>>(
            src, wb_b_in + (size_t)k * 2 * DI * DM, buf_xz, M, 2 * DI, DM);
        fused_xp<<<dim3(KS, M / 64), 256, 0, stream>>>(
            buf_xz, b_convw + (size_t)k * DI * 4, b_convb + (size_t)k * DI,
            wb_xp_b + (size_t)k * 64 * DI, buf_xi, buf_pk, buf_xd, scnt, cbase,
            M, DI, DI / KS, Lb);
        cbase += KS;
        scan_p1<<<Bb * P * DI / 16, 256, 0, stream>>>(
            buf_xi, buf_xd, b_dtw + (size_t)k * DI * R, b_dtb + (size_t)k * DI,
            b_Alog + (size_t)k * DI * 16, buf_wsA, buf_wsB, Bb, Lb, DI, R, P);
        scan_p23<<<Bb * P * DI / 16, 256, 0, stream>>>(
            buf_xi, buf_xd, buf_xz, b_dtw + (size_t)k * DI * R, b_dtb + (size_t)k * DI,
            b_Alog + (size_t)k * DI * 16, b_Dp + (size_t)k * DI,
            buf_wsA, buf_wsB, buf_y, Bb, Lb, DI, R, P);
        if (k == 0)
            gemm_bf16<<<dim3(DM / 64, M / 64), 256, 0, stream>>>(
                buf_y, wb_b_out + (size_t)k * DM * DI, buf_x, M, DM, DI);
        else
            gemm_bf16_tr<<<dim3(DM / 64, M / 64), 256, 0, stream>>>(
                buf_y, wb_b_out + (size_t)k * DM * DI, (float*)d_out, x, M, DM, DI, Lb);
    }
}

// Round 12
// 281.561 us; speedup vs baseline: 18.3564x; 1.4373x over previous
//
#include <hip/hip_runtime.h>
#include <cstdint>

typedef float f32x4 __attribute__((ext_vector_type(4)));
typedef __bf16 bf16x8 __attribute__((ext_vector_type(8)));
typedef __bf16 bf16x4 __attribute__((ext_vector_type(4)));

// Problem constants
// group a: M=512,  DM=512, DI=1024, R=32, P=8,  KS=16, Lb=256
// group b: M=1024, DM=256, DI=512,  R=16, P=16, KS=8,  Lb=512
#define SCAN_TC 32

// ---------------- merged weight conversion ----------------
struct CvtP {
    const float* cs[5]; __bf16* cd[5]; int cn[5]; int nvec;
    const float* xpb; __bf16* xpb_d;
};

__global__ __launch_bounds__(256)
void cvt_all(CvtP p)
{
    const int idx = blockIdx.x * 256 + threadIdx.x;
    if (idx < p.nvec) {
        int off = idx * 4, sgm = 0;
        while (off >= p.cn[sgm]) { off -= p.cn[sgm]; ++sgm; }
        f32x4 v = *(const f32x4*)(p.cs[sgm] + off);
        bf16x4 o;
#pragma unroll
        for (int j = 0; j < 4; ++j) o[j] = (__bf16)v[j];
        *(bf16x4*)(p.cd[sgm] + off) = o;
    } else {
        const int i = idx - p.nvec;
        if (i < 2 * 64 * 512) {
            const int c = i & 511, r = (i >> 9) & 63, l = i >> 15;
            float v = (r < 48) ? p.xpb[((size_t)l * 48 + r) * 512 + c] : 0.f;
            p.xpb_d[i] = (__bf16)v;
        }
    }
}

// ---------------- MFMA GEMM: C(M,N) = A(M,K) @ W(N,K)^T ----------------
__global__ __launch_bounds__(256)
void gemm_bf16(const float* __restrict__ A, const __bf16* __restrict__ W,
               float* __restrict__ C, int M, int N, int K)
{
    __shared__ __bf16 sA[64 * 64];
    __shared__ __bf16 sW[64 * 64];
    const int tid = threadIdx.x;
    const int bm = blockIdx.y * 64, bn = blockIdx.x * 64;
    const int lane = tid & 63, wv = tid >> 6;
    const int m_off = (wv & 1) * 32, n_off = (wv >> 1) * 32;
    const int fr = lane & 15, fq = lane >> 4;
    f32x4 acc[2][2] = {};

    for (int k0 = 0; k0 < K; k0 += 64) {
#pragma unroll
        for (int i = 0; i < 2; ++i) {
            const int cid = i * 256 + tid;
            const int row = cid >> 3, kc = cid & 7;
            const int slot = kc ^ (row & 7);
            const float* sa = A + (size_t)(bm + row) * K + k0 + kc * 8;
            f32x4 v0 = *(const f32x4*)sa;
            f32x4 v1 = *(const f32x4*)(sa + 4);
            bf16x8 ab;
#pragma unroll
            for (int j = 0; j < 4; ++j) { ab[j] = (__bf16)v0[j]; ab[4 + j] = (__bf16)v1[j]; }
            *(bf16x8*)&sA[row * 64 + slot * 8] = ab;
            *(bf16x8*)&sW[row * 64 + slot * 8] =
                *(const bf16x8*)(W + (size_t)(bn + row) * K + k0 + kc * 8);
        }
        __syncthreads();
#pragma unroll
        for (int ks = 0; ks < 2; ++ks) {
            const int kc = ks * 4 + fq;
            const int r0 = m_off + fr, r1 = m_off + 16 + fr;
            const int c0 = n_off + fr, c1 = n_off + 16 + fr;
            bf16x8 a0 = *(const bf16x8*)&sA[r0 * 64 + (kc ^ (r0 & 7)) * 8];
            bf16x8 a1 = *(const bf16x8*)&sA[r1 * 64 + (kc ^ (r1 & 7)) * 8];
            bf16x8 b0 = *(const bf16x8*)&sW[c0 * 64 + (kc ^ (c0 & 7)) * 8];
            bf16x8 b1 = *(const bf16x8*)&sW[c1 * 64 + (kc ^ (c1 & 7)) * 8];
            acc[0][0] = __builtin_amdgcn_mfma_f32_16x16x32_bf16(a0, b0, acc[0][0], 0, 0, 0);
            acc[0][1] = __builtin_amdgcn_mfma_f32_16x16x32_bf16(a0, b1, acc[0][1], 0, 0, 0);
            acc[1][0] = __builtin_amdgcn_mfma_f32_16x16x32_bf16(a1, b0, acc[1][0], 0, 0, 0);
            acc[1][1] = __builtin_amdgcn_mfma_f32_16x16x32_bf16(a1, b1, acc[1][1], 0, 0, 0);
        }
        __syncthreads();
    }
#pragma unroll
    for (int i = 0; i < 2; ++i)
#pragma unroll
        for (int j = 0; j < 2; ++j)
#pragma unroll
            for (int r = 0; r < 4; ++r)
                C[(size_t)(bm + m_off + i * 16 + fq * 4 + r) * N
                  + bn + n_off + j * 16 + fr] = acc[i][j][r];
}

// ---- same GEMM, transposed store: dst[(b*N + col)*Lb + t] (+ optional resid) ----
__global__ __launch_bounds__(256)
void gemm_bf16_tr(const float* __restrict__ A, const __bf16* __restrict__ W,
                  float* __restrict__ dst, const float* __restrict__ resid,
                  int M, int N, int K, int Lb)
{
    __shared__ __bf16 sA[64 * 64];
    __shared__ __bf16 sW[64 * 64];
    const int tid = threadIdx.x;
    const int bm = blockIdx.y * 64, bn = blockIdx.x * 64;
    const int lane = tid & 63, wv = tid >> 6;
    const int m_off = (wv & 1) * 32, n_off = (wv >> 1) * 32;
    const int fr = lane & 15, fq = lane >> 4;
    f32x4 acc[2][2] = {};

    for (int k0 = 0; k0 < K; k0 += 64) {
#pragma unroll
        for (int i = 0; i < 2; ++i) {
            const int cid = i * 256 + tid;
            const int row = cid >> 3, kc = cid & 7;
            const int slot = kc ^ (row & 7);
            const float* sa = A + (size_t)(bm + row) * K + k0 + kc * 8;
            f32x4 v0 = *(const f32x4*)sa;
            f32x4 v1 = *(const f32x4*)(sa + 4);
            bf16x8 ab;
#pragma unroll
            for (int j = 0; j < 4; ++j) { ab[j] = (__bf16)v0[j]; ab[4 + j] = (__bf16)v1[j]; }
            *(bf16x8*)&sA[row * 64 + slot * 8] = ab;
            *(bf16x8*)&sW[row * 64 + slot * 8] =
                *(const bf16x8*)(W + (size_t)(bn + row) * K + k0 + kc * 8);
        }
        __syncthreads();
#pragma unroll
        for (int ks = 0; ks < 2; ++ks) {
            const int kc = ks * 4 + fq;
            const int r0 = m_off + fr, r1 = m_off + 16 + fr;
            const int c0 = n_off + fr, c1 = n_off + 16 + fr;
            bf16x8 a0 = *(const bf16x8*)&sA[r0 * 64 + (kc ^ (r0 & 7)) * 8];
            bf16x8 a1 = *(const bf16x8*)&sA[r1 * 64 + (kc ^ (r1 & 7)) * 8];
            bf16x8 b0 = *(const bf16x8*)&sW[c0 * 64 + (kc ^ (c0 & 7)) * 8];
            bf16x8 b1 = *(const bf16x8*)&sW[c1 * 64 + (kc ^ (c1 & 7)) * 8];
            acc[0][0] = __builtin_amdgcn_mfma_f32_16x16x32_bf16(a0, b0, acc[0][0], 0, 0, 0);
            acc[0][1] = __builtin_amdgcn_mfma_f32_16x16x32_bf16(a0, b1, acc[0][1], 0, 0, 0);
            acc[1][0] = __builtin_amdgcn_mfma_f32_16x16x32_bf16(a1, b0, acc[1][0], 0, 0, 0);
            acc[1][1] = __builtin_amdgcn_mfma_f32_16x16x32_bf16(a1, b1, acc[1][1], 0, 0, 0);
        }
        __syncthreads();
    }
#pragma unroll
    for (int i = 0; i < 2; ++i)
#pragma unroll
        for (int j = 0; j < 2; ++j) {
            const int gn = bn + n_off + j * 16 + fr;
#pragma unroll
            for (int r = 0; r < 4; ++r) {
                const int gm = bm + m_off + i * 16 + fq * 4 + r;
                const int b = gm / Lb, t = gm - b * Lb;
                const size_t o = ((size_t)(b * N + gn)) * Lb + t;
                dst[o] = acc[i][j][r] + (resid ? resid[o] : 0.f);
            }
        }
}

// ------- fused conv+SiLU + split-K x_proj partials: pbuf[ks][M][64] -------
// grid (KS, M/64), KC = DI/KS (=64 here: single K-iteration per block).
__global__ __launch_bounds__(256)
void fused_xp(const float* __restrict__ xz, const float* __restrict__ conv_w,
              const float* __restrict__ conv_b, const __bf16* __restrict__ W,
              float* __restrict__ xi_out, float* __restrict__ pbuf,
              int M, int K, int KC, int Lb)
{
    __shared__ __bf16 sA[64 * 64];
    __shared__ __bf16 sW[64 * 64];
    const int tid = threadIdx.x;
    const int bm = blockIdx.y * 64;
    const int kb = blockIdx.x * KC;
    const int lane = tid & 63, wv = tid >> 6;
    const int m_off = (wv & 1) * 32, n_off = (wv >> 1) * 32;
    const int fr = lane & 15, fq = lane >> 4;
    const int DI = K;
    const int b = bm / Lb;
    const int tbase = bm - b * Lb;
    f32x4 acc[2][2] = {};

    for (int k0 = kb; k0 < kb + KC; k0 += 64) {
#pragma unroll
        for (int i = 0; i < 2; ++i) {
            const int cid = i * 256 + tid;
            const int row = cid >> 3, kc = cid & 7;
            const int slot = kc ^ (row & 7);
            const int d0 = k0 + kc * 8;
            const int t = tbase + row;
            f32x4 a0 = *(const f32x4*)&conv_b[d0];
            f32x4 a1 = *(const f32x4*)&conv_b[d0 + 4];
            f32x4 wc[8];
#pragma unroll
            for (int cch = 0; cch < 8; ++cch)
                wc[cch] = *(const f32x4*)&conv_w[(size_t)(d0 + cch) * 4];
#pragma unroll
            for (int jj = 0; jj < 4; ++jj) {
                const int tt = t - 3 + jj;
                if (tt >= 0) {
                    const float* src = xz + (size_t)(b * Lb + tt) * (2 * DI) + d0;
                    f32x4 v0 = *(const f32x4*)src;
                    f32x4 v1 = *(const f32x4*)(src + 4);
#pragma unroll
                    for (int cch = 0; cch < 4; ++cch) {
                        a0[cch] = fmaf(wc[cch][jj], v0[cch], a0[cch]);
                        a1[cch] = fmaf(wc[4 + cch][jj], v1[cch], a1[cch]);
                    }
                }
            }
            f32x4 r0v, r1v; bf16x8 ab;
#pragma unroll
            for (int cch = 0; cch < 4; ++cch) {
                const float u0 = a0[cch], u1 = a1[cch];
                const float s0 = u0 / (1.f + __expf(-u0));
                const float s1 = u1 / (1.f + __expf(-u1));
                r0v[cch] = s0; r1v[cch] = s1;
                ab[cch] = (__bf16)s0; ab[4 + cch] = (__bf16)s1;
            }
            const size_t mrow = (size_t)(bm + row);
            *(f32x4*)&xi_out[mrow * DI + d0] = r0v;
            *(f32x4*)&xi_out[mrow * DI + d0 + 4] = r1v;
            *(bf16x8*)&sA[row * 64 + slot * 8] = ab;
            *(bf16x8*)&sW[row * 64 + slot * 8] =
                *(const bf16x8*)(W + (size_t)row * K + k0 + kc * 8);
        }
        __syncthreads();
#pragma unroll
        for (int ksu = 0; ksu < 2; ++ksu) {
            const int kc = ksu * 4 + fq;
            const int r0 = m_off + fr, r1 = m_off + 16 + fr;
            const int c0 = n_off + fr, c1 = n_off + 16 + fr;
            bf16x8 a0 = *(const bf16x8*)&sA[r0 * 64 + (kc ^ (r0 & 7)) * 8];
            bf16x8 a1 = *(const bf16x8*)&sA[r1 * 64 + (kc ^ (r1 & 7)) * 8];
            bf16x8 b0 = *(const bf16x8*)&sW[c0 * 64 + (kc ^ (c0 & 7)) * 8];
            bf16x8 b1 = *(const bf16x8*)&sW[c1 * 64 + (kc ^ (c1 & 7)) * 8];
            acc[0][0] = __builtin_amdgcn_mfma_f32_16x16x32_bf16(a0, b0, acc[0][0], 0, 0, 0);
            acc[0][1] = __builtin_amdgcn_mfma_f32_16x16x32_bf16(a0, b1, acc[0][1], 0, 0, 0);
            acc[1][0] = __builtin_amdgcn_mfma_f32_16x16x32_bf16(a1, b0, acc[1][0], 0, 0, 0);
            acc[1][1] = __builtin_amdgcn_mfma_f32_16x16x32_bf16(a1, b1, acc[1][1], 0, 0, 0);
        }
        __syncthreads();
    }
    float* out = pbuf + (size_t)blockIdx.x * M * 64;
#pragma unroll
    for (int i = 0; i < 2; ++i)
#pragma unroll
        for (int jj = 0; jj < 2; ++jj)
#pragma unroll
            for (int r = 0; r < 4; ++r)
                out[(size_t)(bm + m_off + i * 16 + fq * 4 + r) * 64
                    + n_off + jj * 16 + fr] = acc[i][jj][r];
}

// ------- reduce KS partials -> xdbl f32 (reads pbuf exactly once) -------
__global__ __launch_bounds__(256)
void xp_reduce(const float* __restrict__ pbuf, float* __restrict__ xdbl,
               int total, int KS)
{
    const int idx = (blockIdx.x * 256 + threadIdx.x) * 4;
    if (idx >= total) return;
    f32x4 s = {0.f, 0.f, 0.f, 0.f};
    for (int ks = 0; ks < KS; ++ks)
        s += *(const f32x4*)(pbuf + (size_t)ks * total + idx);
    *(f32x4*)(xdbl + idx) = s;
}

// ---------------- scan phase 1 (stage xdbl, dt in f32 LDS) ----------------
__global__ __launch_bounds__(256)
void scan_p1(const float* __restrict__ xi, const float* __restrict__ xdbl,
             const float* __restrict__ dtw, const float* __restrict__ dtb,
             const float* __restrict__ A_log,
             float* __restrict__ wsA, float* __restrict__ wsB,
             int Bb, int Lb, int DI, int R, int P)
{
    __shared__ float s_xd[SCAN_TC][64];
    __shared__ float s_dt[SCAN_TC][16];
    __shared__ float s_xi[SCAN_TC][16];
    __shared__ float s_w[16 * 33];
    __shared__ float s_db[16];
    const int tid = threadIdx.x;
    const int s = tid & 15, dl = tid >> 4;
    const int nDB = DI / 16;
    const int cpb = P * nDB;
    const int b = blockIdx.x / cpb;
    const int rem = blockIdx.x % cpb;
    const int c = rem / nDB;
    const int d0 = (rem % nDB) * 16;
    const int d = d0 + dl;
    const size_t rowbase = (size_t)b * Lb + (size_t)c * SCAN_TC;

    for (int idx = tid; idx < 16 * R; idx += 256)
        s_w[(idx / R) * 33 + (idx % R)] = dtw[(size_t)(d0 + idx / R) * R + idx % R];
    if (tid < 16) s_db[tid] = dtb[d0 + tid];
#pragma unroll
    for (int i = 0; i < 8; ++i) {
        const int e = i * 256 + tid;
        const int tt = e >> 6, col = e & 63;
        s_xd[tt][col] = xdbl[(rowbase + tt) * 64 + col];
    }
#pragma unroll
    for (int i = 0; i < 2; ++i) {
        const int e = i * 256 + tid;
        const int tt = e >> 4, dd = e & 15;
        s_xi[tt][dd] = xi[(rowbase + tt) * DI + d0 + dd];
    }
    __syncthreads();
#pragma unroll
    for (int i = 0; i < 2; ++i) {
        const int pr = i * 256 + tid;
        const int tt = pr >> 4, dd = pr & 15;
        float v = s_db[dd];
        for (int r = 0; r < R; ++r) v = fmaf(s_xd[tt][r], s_w[dd * 33 + r], v);
        s_dt[tt][dd] = fmaxf(v, 0.f) + log1pf(__expf(-fabsf(v)));
    }
    __syncthreads();
    const float A = -__expf(A_log[(size_t)d * 16 + s]);
    float h = 0.f, sdt = 0.f;
#pragma unroll 4
    for (int t = 0; t < SCAN_TC; ++t) {
        const float dtv = s_dt[t][dl];
        const float xv  = s_xi[t][dl];
        const float Bv  = s_xd[t][R + s];
        h = fmaf(__expf(dtv * A), h, dtv * Bv * xv);
        sdt += dtv;
    }
    const size_t o = ((size_t)(b * P + c) * DI + d) * 16 + s;
    wsA[o] = __expf(sdt * A);
    wsB[o] = h;
}

// ---------------- scan phases 2+3 ----------------
__global__ __launch_bounds__(256)
void scan_p23(const float* __restrict__ xi, const float* __restrict__ xdbl,
              const float* __restrict__ xz,
              const float* __restrict__ dtw, const float* __restrict__ dtb,
              const float* __restrict__ A_log, const float* __restrict__ Dp,
              const float* __restrict__ wsA, const float* __restrict__ wsB,
              float* __restrict__ y,
              int Bb, int Lb, int DI, int R, int P)
{
    __shared__ float s_xd[SCAN_TC][64];
    __shared__ float s_dt[SCAN_TC][16];
    __shared__ float s_xi[SCAN_TC][16];
    __shared__ float s_z [SCAN_TC][16];
    __shared__ float s_w[16 * 33];
    __shared__ float s_db[16];
    const int tid = threadIdx.x;
    const int s = tid & 15, dl = tid >> 4;
    const int nDB = DI / 16;
    const int cpb = P * nDB;
    const int b = blockIdx.x / cpb;
    const int rem = blockIdx.x % cpb;
    const int c = rem / nDB;
    const int d0 = (rem % nDB) * 16;
    const int d = d0 + dl;
    const size_t rowbase = (size_t)b * Lb + (size_t)c * SCAN_TC;

    for (int idx = tid; idx < 16 * R; idx += 256)
        s_w[(idx / R) * 33 + (idx % R)] = dtw[(size_t)(d0 + idx / R) * R + idx % R];
    if (tid < 16) s_db[tid] = dtb[d0 + tid];
#pragma unroll
    for (int i = 0; i < 8; ++i) {
        const int e = i * 256 + tid;
        const int tt = e >> 6, col = e & 63;
        s_xd[tt][col] = xdbl[(rowbase + tt) * 64 + col];
    }
#pragma unroll
    for (int i = 0; i < 2; ++i) {
        const int e = i * 256 + tid;
        const int tt = e >> 4, dd = e & 15;
        s_xi[tt][dd] = xi[(rowbase + tt) * DI + d0 + dd];
        s_z [tt][dd] = xz[(rowbase + tt) * (size_t)(2 * DI) + DI + d0 + dd];
    }
    __syncthreads();
#pragma unroll
    for (int i = 0; i < 2; ++i) {
        const int pr = i * 256 + tid;
        const int tt = pr >> 4, dd = pr & 15;
        float v = s_db[dd];
        for (int r = 0; r < R; ++r) v = fmaf(s_xd[tt][r], s_w[dd * 33 + r], v);
        s_dt[tt][dd] = fmaxf(v, 0.f) + log1pf(__expf(-fabsf(v)));
    }
    __syncthreads();
    const float A = -__expf(A_log[(size_t)d * 16 + s]);
    const float Dv = Dp[d];

    float h = 0.f;
    for (int cc = 0; cc < c; ++cc) {
        const size_t oc = ((size_t)(b * P + cc) * DI + d) * 16 + s;
        h = fmaf(wsA[oc], h, wsB[oc]);
    }
#pragma unroll 2
    for (int t = 0; t < SCAN_TC; ++t) {
        const float dtv = s_dt[t][dl];
        const float xv  = s_xi[t][dl];
        const float Bv  = s_xd[t][R + s];
        const float Cv  = s_xd[t][R + 16 + s];
        h = fmaf(__expf(dtv * A), h, dtv * Bv * xv);
        float p = h * Cv;
        p += __shfl_xor(p, 1, 16);
        p += __shfl_xor(p, 2, 16);
        p += __shfl_xor(p, 4, 16);
        p += __shfl_xor(p, 8, 16);
        if (s == 0) {
            const float zv = s_z[t][dl];
            const float sig = __fdividef(zv, 1.f + __expf(-zv));
            y[(rowbase + t) * DI + d] = (p + Dv * xv) * sig;
        }
    }
}

extern "C" void kernel_launch(void* const* d_in, const int* in_sizes, int n_in,
                              void* d_out, int out_size, void* d_ws, size_t ws_size,
                              hipStream_t stream)
{
    const float* x       = (const float*)d_in[0];
    const float* a_in_w  = (const float*)d_in[1];
    const float* a_convw = (const float*)d_in[2];
    const float* a_convb = (const float*)d_in[3];
    const float* a_xproj = (const float*)d_in[4];
    const float* a_dtw   = (const float*)d_in[5];
    const float* a_dtb   = (const float*)d_in[6];
    const float* a_Alog  = (const float*)d_in[7];
    const float* a_Dp    = (const float*)d_in[8];
    const float* a_outw  = (const float*)d_in[9];
    const float* b_in_w  = (const float*)d_in[10];
    const float* b_convw = (const float*)d_in[11];
    const float* b_convb = (const float*)d_in[12];
    const float* b_xproj = (const float*)d_in[13];
    const float* b_dtw   = (const float*)d_in[14];
    const float* b_dtb   = (const float*)d_in[15];
    const float* b_Alog  = (const float*)d_in[16];
    const float* b_Dp    = (const float*)d_in[17];
    const float* b_outw  = (const float*)d_in[18];

    float* ws = (float*)d_ws;
    float* buf_x    = ws;                  // 262144
    float* buf_x2   = buf_x + 262144;      // 262144
    float* buf_xz   = buf_x2 + 262144;     // 1048576
    float* buf_xi   = buf_xz + 1048576;    // 524288
    float* buf_xd   = buf_xi + 524288;     // 65536
    float* buf_y    = buf_xd + 65536;      // 524288
    float* buf_pk   = buf_y + 524288;      // 524288 (KS x M x 64, max 16x512x64)
    float* buf_wsA  = buf_pk + 524288;     // 262144
    float* buf_wsB  = buf_wsA + 262144;    // 262144
    __bf16* wb       = (__bf16*)(buf_wsB + 262144);
    __bf16* wb_a_in  = wb;                 // 2097152
    __bf16* wb_a_out = wb_a_in + 2097152;  // 1048576
    __bf16* wb_b_in  = wb_a_out + 1048576; // 524288
    __bf16* wb_b_out = wb_b_in + 524288;   // 262144
    __bf16* wb_xp_a  = wb_b_out + 262144;  // 131072 (2,64,1024)
    __bf16* wb_xp_b  = wb_xp_a + 131072;   // 65536  (2,64,512) padded

    // merged weight conversion
    {
        CvtP cp;
        cp.cs[0] = a_in_w;  cp.cd[0] = wb_a_in;  cp.cn[0] = 2097152;
        cp.cs[1] = a_outw;  cp.cd[1] = wb_a_out; cp.cn[1] = 1048576;
        cp.cs[2] = b_in_w;  cp.cd[2] = wb_b_in;  cp.cn[2] = 524288;
        cp.cs[3] = b_outw;  cp.cd[3] = wb_b_out; cp.cn[3] = 262144;
        cp.cs[4] = a_xproj; cp.cd[4] = wb_xp_a;  cp.cn[4] = 131072;
        cp.nvec = (2097152 + 1048576 + 524288 + 262144 + 131072) / 4;
        cp.xpb = b_xproj; cp.xpb_d = wb_xp_b;
        const int nthr = cp.nvec + 2 * 64 * 512;
        cvt_all<<<(nthr + 255) / 256, 256, 0, stream>>>(cp);
    }

    // -------- group a: Bb=2, Lb=256, DM=512, DI=1024, R=32, P=8, KS=16 --------
    for (int k = 0; k < 2; ++k) {
        const int Bb = 2, Lb = 256, DM = 512, DI = 1024, R = 32, P = 8, KS = 16;
        const int M = Bb * Lb;
        const float* src = (k == 0) ? x : buf_x;
        gemm_bf16<<<dim3(2 * DI / 64, M / 64), 256, 0, stream>>>(
            src, wb_a_in + (size_t)k * 2 * DI * DM, buf_xz, M, 2 * DI, DM);
        fused_xp<<<dim3(KS, M / 64), 256, 0, stream>>>(
            buf_xz, a_convw + (size_t)k * DI * 4, a_convb + (size_t)k * DI,
            wb_xp_a + (size_t)k * 64 * DI, buf_xi, buf_pk, M, DI, DI / KS, Lb);
        xp_reduce<<<(M * 64 / 4 + 255) / 256, 256, 0, stream>>>(
            buf_pk, buf_xd, M * 64, KS);
        scan_p1<<<Bb * P * DI / 16, 256, 0, stream>>>(
            buf_xi, buf_xd, a_dtw + (size_t)k * DI * R, a_dtb + (size_t)k * DI,
            a_Alog + (size_t)k * DI * 16, buf_wsA, buf_wsB, Bb, Lb, DI, R, P);
        scan_p23<<<Bb * P * DI / 16, 256, 0, stream>>>(
            buf_xi, buf_xd, buf_xz, a_dtw + (size_t)k * DI * R, a_dtb + (size_t)k * DI,
            a_Alog + (size_t)k * DI * 16, a_Dp + (size_t)k * DI,
            buf_wsA, buf_wsB, buf_y, Bb, Lb, DI, R, P);
        if (k == 0)
            gemm_bf16<<<dim3(DM / 64, M / 64), 256, 0, stream>>>(
                buf_y, wb_a_out + (size_t)k * DM * DI, buf_x, M, DM, DI);
        else
            gemm_bf16_tr<<<dim3(DM / 64, M / 64), 256, 0, stream>>>(
                buf_y, wb_a_out + (size_t)k * DM * DI, buf_x2, nullptr, M, DM, DI, Lb);
    }

    // -------- group b: Bb=2, Lb=512, DM=256, DI=512, R=16, P=16, KS=8 --------
    for (int k = 0; k < 2; ++k) {
        const int Bb = 2, Lb = 512, DM = 256, DI = 512, R = 16, P = 16, KS = 8;
        const int M = Bb * Lb;
        const float* src = (k == 0) ? buf_x2 : buf_x;
        gemm_bf16<<<dim3(2 * DI / 64, M / 64), 256, 0, stream>>>(
            src, wb_b_in + (size_t)k * 2 * DI * DM, buf_xz, M, 2 * DI, DM);
        fused_xp<<<dim3(KS, M / 64), 256, 0, stream>>>(
            buf_xz, b_convw + (size_t)k * DI * 4, b_convb + (size_t)k * DI,
            wb_xp_b + (size_t)k * 64 * DI, buf_xi, buf_pk, M, DI, DI / KS, Lb);
        xp_reduce<<<(M * 64 / 4 + 255) / 256, 256, 0, stream>>>(
            buf_pk, buf_xd, M * 64, KS);
        scan_p1<<<Bb * P * DI / 16, 256, 0, stream>>>(
            buf_xi, buf_xd, b_dtw + (size_t)k * DI * R, b_dtb + (size_t)k * DI,
            b_Alog + (size_t)k * DI * 16, buf_wsA, buf_wsB, Bb, Lb, DI, R, P);
        scan_p23<<<Bb * P * DI / 16, 256, 0, stream>>>(
            buf_xi, buf_xd, buf_xz, b_dtw + (size_t)k * DI * R, b_dtb + (size_t)k * DI,
            b_Alog + (size_t)k * DI * 16, b_Dp + (size_t)k * DI,
            buf_wsA, buf_wsB, buf_y, Bb, Lb, DI, R, P);
        if (k == 0)
            gemm_bf16<<<dim3(DM / 64, M / 64), 256, 0, stream>>>(
                buf_y, wb_b_out + (size_t)k * DM * DI, buf_x, M, DM, DI);
        else
            gemm_bf16_tr<<<dim3(DM / 64, M / 64), 256, 0, stream>>>(
                buf_y, wb_b_out + (size_t)k * DM * DI, (float*)d_out, x, M, DM, DI, Lb);
    }
}

// Round 13
// 218.886 us; speedup vs baseline: 23.6125x; 1.2863x over previous
//
#include <hip/hip_runtime.h>
#include <cstdint>

typedef float f32x4 __attribute__((ext_vector_type(4)));
typedef __bf16 bf16x8 __attribute__((ext_vector_type(8)));
typedef __bf16 bf16x4 __attribute__((ext_vector_type(4)));

// Problem constants
// group a: M=512,  DM=512, DI=1024, R=32, P=8,  KS=16, Lb=256
// group b: M=1024, DM=256, DI=512,  R=16, P=16, KS=8,  Lb=512
#define SCAN_TC 32

// ---------------- merged weight conversion ----------------
struct CvtP {
    const float* cs[5]; __bf16* cd[5]; int cn[5]; int nvec;
    const float* xpb; __bf16* xpb_d;
};

__global__ __launch_bounds__(256)
void cvt_all(CvtP p)
{
    const int idx = blockIdx.x * 256 + threadIdx.x;
    if (idx < p.nvec) {
        int off = idx * 4, sgm = 0;
        while (off >= p.cn[sgm]) { off -= p.cn[sgm]; ++sgm; }
        f32x4 v = *(const f32x4*)(p.cs[sgm] + off);
        bf16x4 o;
#pragma unroll
        for (int j = 0; j < 4; ++j) o[j] = (__bf16)v[j];
        *(bf16x4*)(p.cd[sgm] + off) = o;
    } else {
        const int i = idx - p.nvec;
        if (i < 2 * 64 * 512) {
            const int c = i & 511, r = (i >> 9) & 63, l = i >> 15;
            float v = (r < 48) ? p.xpb[((size_t)l * 48 + r) * 512 + c] : 0.f;
            p.xpb_d[i] = (__bf16)v;
        }
    }
}

// -------- MFMA GEMM, f32 A: C(M,N) = A(M,K) @ W(N,K)^T (first in_proj only) --------
__global__ __launch_bounds__(256)
void gemm_f32A(const float* __restrict__ A, const __bf16* __restrict__ W,
               float* __restrict__ C, int M, int N, int K)
{
    __shared__ __bf16 sA[64 * 64];
    __shared__ __bf16 sW[64 * 64];
    const int tid = threadIdx.x;
    const int bm = blockIdx.y * 64, bn = blockIdx.x * 64;
    const int lane = tid & 63, wv = tid >> 6;
    const int m_off = (wv & 1) * 32, n_off = (wv >> 1) * 32;
    const int fr = lane & 15, fq = lane >> 4;
    f32x4 acc[2][2] = {};

    for (int k0 = 0; k0 < K; k0 += 64) {
#pragma unroll
        for (int i = 0; i < 2; ++i) {
            const int cid = i * 256 + tid;
            const int row = cid >> 3, kc = cid & 7;
            const int slot = kc ^ (row & 7);
            const float* sa = A + (size_t)(bm + row) * K + k0 + kc * 8;
            f32x4 v0 = *(const f32x4*)sa;
            f32x4 v1 = *(const f32x4*)(sa + 4);
            bf16x8 ab;
#pragma unroll
            for (int j = 0; j < 4; ++j) { ab[j] = (__bf16)v0[j]; ab[4 + j] = (__bf16)v1[j]; }
            *(bf16x8*)&sA[row * 64 + slot * 8] = ab;
            *(bf16x8*)&sW[row * 64 + slot * 8] =
                *(const bf16x8*)(W + (size_t)(bn + row) * K + k0 + kc * 8);
        }
        __syncthreads();
#pragma unroll
        for (int ks = 0; ks < 2; ++ks) {
            const int kc = ks * 4 + fq;
            const int r0 = m_off + fr, r1 = m_off + 16 + fr;
            const int c0 = n_off + fr, c1 = n_off + 16 + fr;
            bf16x8 a0 = *(const bf16x8*)&sA[r0 * 64 + (kc ^ (r0 & 7)) * 8];
            bf16x8 a1 = *(const bf16x8*)&sA[r1 * 64 + (kc ^ (r1 & 7)) * 8];
            bf16x8 b0 = *(const bf16x8*)&sW[c0 * 64 + (kc ^ (c0 & 7)) * 8];
            bf16x8 b1 = *(const bf16x8*)&sW[c1 * 64 + (kc ^ (c1 & 7)) * 8];
            acc[0][0] = __builtin_amdgcn_mfma_f32_16x16x32_bf16(a0, b0, acc[0][0], 0, 0, 0);
            acc[0][1] = __builtin_amdgcn_mfma_f32_16x16x32_bf16(a0, b1, acc[0][1], 0, 0, 0);
            acc[1][0] = __builtin_amdgcn_mfma_f32_16x16x32_bf16(a1, b0, acc[1][0], 0, 0, 0);
            acc[1][1] = __builtin_amdgcn_mfma_f32_16x16x32_bf16(a1, b1, acc[1][1], 0, 0, 0);
        }
        __syncthreads();
    }
#pragma unroll
    for (int i = 0; i < 2; ++i)
#pragma unroll
        for (int j = 0; j < 2; ++j)
#pragma unroll
            for (int r = 0; r < 4; ++r)
                C[(size_t)(bm + m_off + i * 16 + fq * 4 + r) * N
                  + bn + n_off + j * 16 + fr] = acc[i][j][r];
}

// -------- MFMA GEMM, bf16 A: C(M,N) f32 = A(M,K)bf16 @ W(N,K)^T (in_proj 2..4) --------
__global__ __launch_bounds__(256)
void gemm_b16A(const __bf16* __restrict__ A, const __bf16* __restrict__ W,
               float* __restrict__ C, int M, int N, int K)
{
    __shared__ __bf16 sA[64 * 64];
    __shared__ __bf16 sW[64 * 64];
    const int tid = threadIdx.x;
    const int bm = blockIdx.y * 64, bn = blockIdx.x * 64;
    const int lane = tid & 63, wv = tid >> 6;
    const int m_off = (wv & 1) * 32, n_off = (wv >> 1) * 32;
    const int fr = lane & 15, fq = lane >> 4;
    f32x4 acc[2][2] = {};

    for (int k0 = 0; k0 < K; k0 += 64) {
#pragma unroll
        for (int i = 0; i < 2; ++i) {
            const int cid = i * 256 + tid;
            const int row = cid >> 3, kc = cid & 7;
            const int slot = kc ^ (row & 7);
            *(bf16x8*)&sA[row * 64 + slot * 8] =
                *(const bf16x8*)(A + (size_t)(bm + row) * K + k0 + kc * 8);
            *(bf16x8*)&sW[row * 64 + slot * 8] =
                *(const bf16x8*)(W + (size_t)(bn + row) * K + k0 + kc * 8);
        }
        __syncthreads();
#pragma unroll
        for (int ks = 0; ks < 2; ++ks) {
            const int kc = ks * 4 + fq;
            const int r0 = m_off + fr, r1 = m_off + 16 + fr;
            const int c0 = n_off + fr, c1 = n_off + 16 + fr;
            bf16x8 a0 = *(const bf16x8*)&sA[r0 * 64 + (kc ^ (r0 & 7)) * 8];
            bf16x8 a1 = *(const bf16x8*)&sA[r1 * 64 + (kc ^ (r1 & 7)) * 8];
            bf16x8 b0 = *(const bf16x8*)&sW[c0 * 64 + (kc ^ (c0 & 7)) * 8];
            bf16x8 b1 = *(const bf16x8*)&sW[c1 * 64 + (kc ^ (c1 & 7)) * 8];
            acc[0][0] = __builtin_amdgcn_mfma_f32_16x16x32_bf16(a0, b0, acc[0][0], 0, 0, 0);
            acc[0][1] = __builtin_amdgcn_mfma_f32_16x16x32_bf16(a0, b1, acc[0][1], 0, 0, 0);
            acc[1][0] = __builtin_amdgcn_mfma_f32_16x16x32_bf16(a1, b0, acc[1][0], 0, 0, 0);
            acc[1][1] = __builtin_amdgcn_mfma_f32_16x16x32_bf16(a1, b1, acc[1][1], 0, 0, 0);
        }
        __syncthreads();
    }
#pragma unroll
    for (int i = 0; i < 2; ++i)
#pragma unroll
        for (int j = 0; j < 2; ++j)
#pragma unroll
            for (int r = 0; r < 4; ++r)
                C[(size_t)(bm + m_off + i * 16 + fq * 4 + r) * N
                  + bn + n_off + j * 16 + fr] = acc[i][j][r];
}

// -------- out_proj: direct-load GEMM, per-wave 16x16, block 32x32, grid (N/32, M/32) --------
// mode 0: dst bf16 row-major (M,N). mode 1: dst bf16 tr [(b*N+col)*Lb+t].
// mode 2: dst f32 tr + resid.
__global__ __launch_bounds__(256)
void gemm_out(const __bf16* __restrict__ A, const __bf16* __restrict__ W,
              void* __restrict__ dst, const float* __restrict__ resid,
              int M, int N, int K, int Lb, int mode)
{
    const int tid = threadIdx.x, lane = tid & 63, wv = tid >> 6;
    const int bm = blockIdx.y * 32 + (wv & 1) * 16;
    const int bn = blockIdx.x * 32 + (wv >> 1) * 16;
    const int fr = lane & 15, fq = lane >> 4;
    const __bf16* arow = A + (size_t)(bm + fr) * K + fq * 8;
    const __bf16* brow = W + (size_t)(bn + fr) * K + fq * 8;
    f32x4 acc0 = {}, acc1 = {};
#pragma unroll 2
    for (int k0 = 0; k0 < K; k0 += 64) {
        bf16x8 a0 = *(const bf16x8*)(arow + k0);
        bf16x8 b0 = *(const bf16x8*)(brow + k0);
        bf16x8 a1 = *(const bf16x8*)(arow + k0 + 32);
        bf16x8 b1 = *(const bf16x8*)(brow + k0 + 32);
        acc0 = __builtin_amdgcn_mfma_f32_16x16x32_bf16(a0, b0, acc0, 0, 0, 0);
        acc1 = __builtin_amdgcn_mfma_f32_16x16x32_bf16(a1, b1, acc1, 0, 0, 0);
    }
    f32x4 acc = acc0 + acc1;
    const int col = bn + fr;
#pragma unroll
    for (int r = 0; r < 4; ++r) {
        const int gm = bm + fq * 4 + r;
        if (mode == 0) {
            ((__bf16*)dst)[(size_t)gm * N + col] = (__bf16)acc[r];
        } else {
            const int b = gm / Lb, t = gm - b * Lb;
            const size_t o = ((size_t)(b * N + col)) * Lb + t;
            if (mode == 1) ((__bf16*)dst)[o] = (__bf16)acc[r];
            else ((float*)dst)[o] = acc[r] + resid[o];
        }
    }
}

// ------- fused conv+SiLU + split-K x_proj partials: pbuf[ks][M][64] -------
__global__ __launch_bounds__(256)
void fused_xp(const float* __restrict__ xz, const float* __restrict__ conv_w,
              const float* __restrict__ conv_b, const __bf16* __restrict__ W,
              float* __restrict__ xi_out, float* __restrict__ pbuf,
              int M, int K, int KC, int Lb)
{
    __shared__ __bf16 sA[64 * 64];
    __shared__ __bf16 sW[64 * 64];
    const int tid = threadIdx.x;
    const int bm = blockIdx.y * 64;
    const int kb = blockIdx.x * KC;
    const int lane = tid & 63, wv = tid >> 6;
    const int m_off = (wv & 1) * 32, n_off = (wv >> 1) * 32;
    const int fr = lane & 15, fq = lane >> 4;
    const int DI = K;
    const int b = bm / Lb;
    const int tbase = bm - b * Lb;
    f32x4 acc[2][2] = {};

    for (int k0 = kb; k0 < kb + KC; k0 += 64) {
#pragma unroll
        for (int i = 0; i < 2; ++i) {
            const int cid = i * 256 + tid;
            const int row = cid >> 3, kc = cid & 7;
            const int slot = kc ^ (row & 7);
            const int d0 = k0 + kc * 8;
            const int t = tbase + row;
            f32x4 a0 = *(const f32x4*)&conv_b[d0];
            f32x4 a1 = *(const f32x4*)&conv_b[d0 + 4];
            f32x4 wc[8];
#pragma unroll
            for (int cch = 0; cch < 8; ++cch)
                wc[cch] = *(const f32x4*)&conv_w[(size_t)(d0 + cch) * 4];
#pragma unroll
            for (int jj = 0; jj < 4; ++jj) {
                const int tt = t - 3 + jj;
                if (tt >= 0) {
                    const float* src = xz + (size_t)(b * Lb + tt) * (2 * DI) + d0;
                    f32x4 v0 = *(const f32x4*)src;
                    f32x4 v1 = *(const f32x4*)(src + 4);
#pragma unroll
                    for (int cch = 0; cch < 4; ++cch) {
                        a0[cch] = fmaf(wc[cch][jj], v0[cch], a0[cch]);
                        a1[cch] = fmaf(wc[4 + cch][jj], v1[cch], a1[cch]);
                    }
                }
            }
            f32x4 r0v, r1v; bf16x8 ab;
#pragma unroll
            for (int cch = 0; cch < 4; ++cch) {
                const float u0 = a0[cch], u1 = a1[cch];
                const float s0 = u0 / (1.f + __expf(-u0));
                const float s1 = u1 / (1.f + __expf(-u1));
                r0v[cch] = s0; r1v[cch] = s1;
                ab[cch] = (__bf16)s0; ab[4 + cch] = (__bf16)s1;
            }
            const size_t mrow = (size_t)(bm + row);
            *(f32x4*)&xi_out[mrow * DI + d0] = r0v;
            *(f32x4*)&xi_out[mrow * DI + d0 + 4] = r1v;
            *(bf16x8*)&sA[row * 64 + slot * 8] = ab;
            *(bf16x8*)&sW[row * 64 + slot * 8] =
                *(const bf16x8*)(W + (size_t)row * K + k0 + kc * 8);
        }
        __syncthreads();
#pragma unroll
        for (int ksu = 0; ksu < 2; ++ksu) {
            const int kc = ksu * 4 + fq;
            const int r0 = m_off + fr, r1 = m_off + 16 + fr;
            const int c0 = n_off + fr, c1 = n_off + 16 + fr;
            bf16x8 a0 = *(const bf16x8*)&sA[r0 * 64 + (kc ^ (r0 & 7)) * 8];
            bf16x8 a1 = *(const bf16x8*)&sA[r1 * 64 + (kc ^ (r1 & 7)) * 8];
            bf16x8 b0 = *(const bf16x8*)&sW[c0 * 64 + (kc ^ (c0 & 7)) * 8];
            bf16x8 b1 = *(const bf16x8*)&sW[c1 * 64 + (kc ^ (c1 & 7)) * 8];
            acc[0][0] = __builtin_amdgcn_mfma_f32_16x16x32_bf16(a0, b0, acc[0][0], 0, 0, 0);
            acc[0][1] = __builtin_amdgcn_mfma_f32_16x16x32_bf16(a0, b1, acc[0][1], 0, 0, 0);
            acc[1][0] = __builtin_amdgcn_mfma_f32_16x16x32_bf16(a1, b0, acc[1][0], 0, 0, 0);
            acc[1][1] = __builtin_amdgcn_mfma_f32_16x16x32_bf16(a1, b1, acc[1][1], 0, 0, 0);
        }
        __syncthreads();
    }
    float* out = pbuf + (size_t)blockIdx.x * M * 64;
#pragma unroll
    for (int i = 0; i < 2; ++i)
#pragma unroll
        for (int jj = 0; jj < 2; ++jj)
#pragma unroll
            for (int r = 0; r < 4; ++r)
                out[(size_t)(bm + m_off + i * 16 + fq * 4 + r) * 64
                    + n_off + jj * 16 + fr] = acc[i][jj][r];
}

// ------- reduce KS partials -> xdbl f32 (reads pbuf exactly once) -------
__global__ __launch_bounds__(256)
void xp_reduce(const float* __restrict__ pbuf, float* __restrict__ xdbl,
               int total, int KS)
{
    const int idx = (blockIdx.x * 256 + threadIdx.x) * 4;
    if (idx >= total) return;
    f32x4 s = {0.f, 0.f, 0.f, 0.f};
    for (int ks = 0; ks < KS; ++ks)
        s += *(const f32x4*)(pbuf + (size_t)ks * total + idx);
    *(f32x4*)(xdbl + idx) = s;
}

// ---------------- scan phase 1 (stage xdbl, dt in f32 LDS) ----------------
__global__ __launch_bounds__(256)
void scan_p1(const float* __restrict__ xi, const float* __restrict__ xdbl,
             const float* __restrict__ dtw, const float* __restrict__ dtb,
             const float* __restrict__ A_log,
             float* __restrict__ wsA, float* __restrict__ wsB,
             int Bb, int Lb, int DI, int R, int P)
{
    __shared__ float s_xd[SCAN_TC][64];
    __shared__ float s_dt[SCAN_TC][16];
    __shared__ float s_xi[SCAN_TC][16];
    __shared__ float s_w[16 * 33];
    __shared__ float s_db[16];
    const int tid = threadIdx.x;
    const int s = tid & 15, dl = tid >> 4;
    const int nDB = DI / 16;
    const int cpb = P * nDB;
    const int b = blockIdx.x / cpb;
    const int rem = blockIdx.x % cpb;
    const int c = rem / nDB;
    const int d0 = (rem % nDB) * 16;
    const int d = d0 + dl;
    const size_t rowbase = (size_t)b * Lb + (size_t)c * SCAN_TC;

    for (int idx = tid; idx < 16 * R; idx += 256)
        s_w[(idx / R) * 33 + (idx % R)] = dtw[(size_t)(d0 + idx / R) * R + idx % R];
    if (tid < 16) s_db[tid] = dtb[d0 + tid];
#pragma unroll
    for (int i = 0; i < 8; ++i) {
        const int e = i * 256 + tid;
        const int tt = e >> 6, col = e & 63;
        s_xd[tt][col] = xdbl[(rowbase + tt) * 64 + col];
    }
#pragma unroll
    for (int i = 0; i < 2; ++i) {
        const int e = i * 256 + tid;
        const int tt = e >> 4, dd = e & 15;
        s_xi[tt][dd] = xi[(rowbase + tt) * DI + d0 + dd];
    }
    __syncthreads();
#pragma unroll
    for (int i = 0; i < 2; ++i) {
        const int pr = i * 256 + tid;
        const int tt = pr >> 4, dd = pr & 15;
        float v = s_db[dd];
        for (int r = 0; r < R; ++r) v = fmaf(s_xd[tt][r], s_w[dd * 33 + r], v);
        s_dt[tt][dd] = fmaxf(v, 0.f) + log1pf(__expf(-fabsf(v)));
    }
    __syncthreads();
    const float A = -__expf(A_log[(size_t)d * 16 + s]);
    float h = 0.f, sdt = 0.f;
#pragma unroll 4
    for (int t = 0; t < SCAN_TC; ++t) {
        const float dtv = s_dt[t][dl];
        const float xv  = s_xi[t][dl];
        const float Bv  = s_xd[t][R + s];
        h = fmaf(__expf(dtv * A), h, dtv * Bv * xv);
        sdt += dtv;
    }
    const size_t o = ((size_t)(b * P + c) * DI + d) * 16 + s;
    wsA[o] = __expf(sdt * A);
    wsB[o] = h;
}

// ---------------- scan phases 2+3 (emit y as bf16) ----------------
__global__ __launch_bounds__(256)
void scan_p23(const float* __restrict__ xi, const float* __restrict__ xdbl,
              const float* __restrict__ xz,
              const float* __restrict__ dtw, const float* __restrict__ dtb,
              const float* __restrict__ A_log, const float* __restrict__ Dp,
              const float* __restrict__ wsA, const float* __restrict__ wsB,
              __bf16* __restrict__ y,
              int Bb, int Lb, int DI, int R, int P)
{
    __shared__ float s_xd[SCAN_TC][64];
    __shared__ float s_dt[SCAN_TC][16];
    __shared__ float s_xi[SCAN_TC][16];
    __shared__ float s_z [SCAN_TC][16];
    __shared__ float s_w[16 * 33];
    __shared__ float s_db[16];
    const int tid = threadIdx.x;
    const int s = tid & 15, dl = tid >> 4;
    const int nDB = DI / 16;
    const int cpb = P * nDB;
    const int b = blockIdx.x / cpb;
    const int rem = blockIdx.x % cpb;
    const int c = rem / nDB;
    const int d0 = (rem % nDB) * 16;
    const int d = d0 + dl;
    const size_t rowbase = (size_t)b * Lb + (size_t)c * SCAN_TC;

    for (int idx = tid; idx < 16 * R; idx += 256)
        s_w[(idx / R) * 33 + (idx % R)] = dtw[(size_t)(d0 + idx / R) * R + idx % R];
    if (tid < 16) s_db[tid] = dtb[d0 + tid];
#pragma unroll
    for (int i = 0; i < 8; ++i) {
        const int e = i * 256 + tid;
        const int tt = e >> 6, col = e & 63;
        s_xd[tt][col] = xdbl[(rowbase + tt) * 64 + col];
    }
#pragma unroll
    for (int i = 0; i < 2; ++i) {
        const int e = i * 256 + tid;
        const int tt = e >> 4, dd = e & 15;
        s_xi[tt][dd] = xi[(rowbase + tt) * DI + d0 + dd];
        s_z [tt][dd] = xz[(rowbase + tt) * (size_t)(2 * DI) + DI + d0 + dd];
    }
    __syncthreads();
#pragma unroll
    for (int i = 0; i < 2; ++i) {
        const int pr = i * 256 + tid;
        const int tt = pr >> 4, dd = pr & 15;
        float v = s_db[dd];
        for (int r = 0; r < R; ++r) v = fmaf(s_xd[tt][r], s_w[dd * 33 + r], v);
        s_dt[tt][dd] = fmaxf(v, 0.f) + log1pf(__expf(-fabsf(v)));
    }
    __syncthreads();
    const float A = -__expf(A_log[(size_t)d * 16 + s]);
    const float Dv = Dp[d];

    float h = 0.f;
    for (int cc = 0; cc < c; ++cc) {
        const size_t oc = ((size_t)(b * P + cc) * DI + d) * 16 + s;
        h = fmaf(wsA[oc], h, wsB[oc]);
    }
#pragma unroll 2
    for (int t = 0; t < SCAN_TC; ++t) {
        const float dtv = s_dt[t][dl];
        const float xv  = s_xi[t][dl];
        const float Bv  = s_xd[t][R + s];
        const float Cv  = s_xd[t][R + 16 + s];
        h = fmaf(__expf(dtv * A), h, dtv * Bv * xv);
        float p = h * Cv;
        p += __shfl_xor(p, 1, 16);
        p += __shfl_xor(p, 2, 16);
        p += __shfl_xor(p, 4, 16);
        p += __shfl_xor(p, 8, 16);
        if (s == 0) {
            const float zv = s_z[t][dl];
            const float sig = __fdividef(zv, 1.f + __expf(-zv));
            y[(rowbase + t) * DI + d] = (__bf16)((p + Dv * xv) * sig);
        }
    }
}

extern "C" void kernel_launch(void* const* d_in, const int* in_sizes, int n_in,
                              void* d_out, int out_size, void* d_ws, size_t ws_size,
                              hipStream_t stream)
{
    const float* x       = (const float*)d_in[0];
    const float* a_in_w  = (const float*)d_in[1];
    const float* a_convw = (const float*)d_in[2];
    const float* a_convb = (const float*)d_in[3];
    const float* a_xproj = (const float*)d_in[4];
    const float* a_dtw   = (const float*)d_in[5];
    const float* a_dtb   = (const float*)d_in[6];
    const float* a_Alog  = (const float*)d_in[7];
    const float* a_Dp    = (const float*)d_in[8];
    const float* a_outw  = (const float*)d_in[9];
    const float* b_in_w  = (const float*)d_in[10];
    const float* b_convw = (const float*)d_in[11];
    const float* b_convb = (const float*)d_in[12];
    const float* b_xproj = (const float*)d_in[13];
    const float* b_dtw   = (const float*)d_in[14];
    const float* b_dtb   = (const float*)d_in[15];
    const float* b_Alog  = (const float*)d_in[16];
    const float* b_Dp    = (const float*)d_in[17];
    const float* b_outw  = (const float*)d_in[18];

    float* ws = (float*)d_ws;
    float* buf_xz   = ws;                  // 1048576
    float* buf_xi   = buf_xz + 1048576;    // 524288
    float* buf_xd   = buf_xi + 524288;     // 65536
    float* buf_pk   = buf_xd + 65536;      // 524288 (KS x M x 64, max 16x512x64)
    float* buf_wsA  = buf_pk + 524288;     // 262144
    float* buf_wsB  = buf_wsA + 262144;    // 262144
    __bf16* wb       = (__bf16*)(buf_wsB + 262144);
    __bf16* wb_a_in  = wb;                 // 2097152
    __bf16* wb_a_out = wb_a_in + 2097152;  // 1048576
    __bf16* wb_b_in  = wb_a_out + 1048576; // 524288
    __bf16* wb_b_out = wb_b_in + 524288;   // 262144
    __bf16* wb_xp_a  = wb_b_out + 262144;  // 131072 (2,64,1024)
    __bf16* wb_xp_b  = wb_xp_a + 131072;   // 65536  (2,64,512) padded
    __bf16* buf_xb   = wb_xp_b + 65536;    // 262144 (layer-to-layer activations)
    __bf16* buf_x2b  = buf_xb + 262144;    // 262144 (transposed a->b handoff)
    __bf16* buf_yb   = buf_x2b + 262144;   // 524288 (scan output)

    // merged weight conversion
    {
        CvtP cp;
        cp.cs[0] = a_in_w;  cp.cd[0] = wb_a_in;  cp.cn[0] = 2097152;
        cp.cs[1] = a_outw;  cp.cd[1] = wb_a_out; cp.cn[1] = 1048576;
        cp.cs[2] = b_in_w;  cp.cd[2] = wb_b_in;  cp.cn[2] = 524288;
        cp.cs[3] = b_outw;  cp.cd[3] = wb_b_out; cp.cn[3] = 262144;
        cp.cs[4] = a_xproj; cp.cd[4] = wb_xp_a;  cp.cn[4] = 131072;
        cp.nvec = (2097152 + 1048576 + 524288 + 262144 + 131072) / 4;
        cp.xpb = b_xproj; cp.xpb_d = wb_xp_b;
        const int nthr = cp.nvec + 2 * 64 * 512;
        cvt_all<<<(nthr + 255) / 256, 256, 0, stream>>>(cp);
    }

    // -------- group a: Bb=2, Lb=256, DM=512, DI=1024, R=32, P=8, KS=16 --------
    for (int k = 0; k < 2; ++k) {
        const int Bb = 2, Lb = 256, DM = 512, DI = 1024, R = 32, P = 8, KS = 16;
        const int M = Bb * Lb;
        if (k == 0)
            gemm_f32A<<<dim3(2 * DI / 64, M / 64), 256, 0, stream>>>(
                x, wb_a_in + (size_t)k * 2 * DI * DM, buf_xz, M, 2 * DI, DM);
        else
            gemm_b16A<<<dim3(2 * DI / 64, M / 64), 256, 0, stream>>>(
                buf_xb, wb_a_in + (size_t)k * 2 * DI * DM, buf_xz, M, 2 * DI, DM);
        fused_xp<<<dim3(KS, M / 64), 256, 0, stream>>>(
            buf_xz, a_convw + (size_t)k * DI * 4, a_convb + (size_t)k * DI,
            wb_xp_a + (size_t)k * 64 * DI, buf_xi, buf_pk, M, DI, DI / KS, Lb);
        xp_reduce<<<(M * 64 / 4 + 255) / 256, 256, 0, stream>>>(
            buf_pk, buf_xd, M * 64, KS);
        scan_p1<<<Bb * P * DI / 16, 256, 0, stream>>>(
            buf_xi, buf_xd, a_dtw + (size_t)k * DI * R, a_dtb + (size_t)k * DI,
            a_Alog + (size_t)k * DI * 16, buf_wsA, buf_wsB, Bb, Lb, DI, R, P);
        scan_p23<<<Bb * P * DI / 16, 256, 0, stream>>>(
            buf_xi, buf_xd, buf_xz, a_dtw + (size_t)k * DI * R, a_dtb + (size_t)k * DI,
            a_Alog + (size_t)k * DI * 16, a_Dp + (size_t)k * DI,
            buf_wsA, buf_wsB, buf_yb, Bb, Lb, DI, R, P);
        if (k == 0)
            gemm_out<<<dim3(DM / 32, M / 32), 256, 0, stream>>>(
                buf_yb, wb_a_out + (size_t)k * DM * DI, buf_xb, nullptr,
                M, DM, DI, Lb, 0);
        else
            gemm_out<<<dim3(DM / 32, M / 32), 256, 0, stream>>>(
                buf_yb, wb_a_out + (size_t)k * DM * DI, buf_x2b, nullptr,
                M, DM, DI, Lb, 1);
    }

    // -------- group b: Bb=2, Lb=512, DM=256, DI=512, R=16, P=16, KS=8 --------
    for (int k = 0; k < 2; ++k) {
        const int Bb = 2, Lb = 512, DM = 256, DI = 512, R = 16, P = 16, KS = 8;
        const int M = Bb * Lb;
        const __bf16* src = (k == 0) ? buf_x2b : buf_xb;
        gemm_b16A<<<dim3(2 * DI / 64, M / 64), 256, 0, stream>>>(
            src, wb_b_in + (size_t)k * 2 * DI * DM, buf_xz, M, 2 * DI, DM);
        fused_xp<<<dim3(KS, M / 64), 256, 0, stream>>>(
            buf_xz, b_convw + (size_t)k * DI * 4, b_convb + (size_t)k * DI,
            wb_xp_b + (size_t)k * 64 * DI, buf_xi, buf_pk, M, DI, DI / KS, Lb);
        xp_reduce<<<(M * 64 / 4 + 255) / 256, 256, 0, stream>>>(
            buf_pk, buf_xd, M * 64, KS);
        scan_p1<<<Bb * P * DI / 16, 256, 0, stream>>>(
            buf_xi, buf_xd, b_dtw + (size_t)k * DI * R, b_dtb + (size_t)k * DI,
            b_Alog + (size_t)k * DI * 16, buf_wsA, buf_wsB, Bb, Lb, DI, R, P);
        scan_p23<<<Bb * P * DI / 16, 256, 0, stream>>>(
            buf_xi, buf_xd, buf_xz, b_dtw + (size_t)k * DI * R, b_dtb + (size_t)k * DI,
            b_Alog + (size_t)k * DI * 16, b_Dp + (size_t)k * DI,
            buf_wsA, buf_wsB, buf_yb, Bb, Lb, DI, R, P);
        if (k == 0)
            gemm_out<<<dim3(DM / 32, M / 32), 256, 0, stream>>>(
                buf_yb, wb_b_out + (size_t)k * DM * DI, buf_xb, nullptr,
                M, DM, DI, Lb, 0);
        else
            gemm_out<<<dim3(DM / 32, M / 32), 256, 0, stream>>>(
                buf_yb, wb_b_out + (size_t)k * DM * DI, d_out, x,
                M, DM, DI, Lb, 2);
    }
}